// Round 5
// baseline (578.246 us; speedup 1.0000x reference)
//
#include <hip/hip_runtime.h>

// 1-NN via 3-term bf16-split MFMA + provably-safe exact rescore.
// argmin_j ||x_i - y_j||^2 == argmin_j (0.5||y_j||^2 - x_i.y_j).
// Pass A (MFMA): d~ = h_j - (xhi.yhi + xhi.ylo + xlo.yhi), per-(q,slice) top-2 min.
// Pass B: candidates = {j : d~ <= min_q + EPS}; 1 candidate -> done; else exact
// fp32 rescore (serial or slice-rescan worklist) with (dist,idx)-lex atomicMin.
// EPS=0.0625 is >=100x the bf16-split error bound (~5e-4).
//
// Round 5: no LDS in pass A. Each lane's B-frag (8 contiguous k of one y-row)
// is one global dwordx4 -> registers. Round 4's LDS staging had ZERO cross-wave
// reuse (wave w only reads rows w*16+l15) and cost 2 barriers/chunk + 1.7e7
// bank-conflict cycles. Barrier-free waves + 2-deep A/B register pipeline.

#define NQ 8192
#define NM 32768
#define ND 128
#define BT 256
#define NSLICE 8
#define SLICE (NM / NSLICE)   // 4096
#define QB 32                 // queries per block (pass A)
#define EPS 0.0625f
#define WLCAP 16384

using bf16x8 = __attribute__((ext_vector_type(8))) short;
using f32x4  = __attribute__((ext_vector_type(4))) float;

__device__ __forceinline__ unsigned short bf16r(float f) {
  unsigned u = __float_as_uint(f);
  u += 0x7FFFu + ((u >> 16) & 1u);
  return (unsigned short)(u >> 16);
}
__device__ __forceinline__ float bf2f(unsigned short h) {
  return __uint_as_float(((unsigned)h) << 16);
}
__device__ __forceinline__ unsigned long long packsd(float s, int j) {
  unsigned u = __float_as_uint(s);
  u ^= (u & 0x80000000u) ? 0xFFFFFFFFu : 0x80000000u;  // monotone float->uint
  return (((unsigned long long)u) << 32) | (unsigned)j;
}

// ---- split y -> bf16 hi/lo arrays (plain row-major); also zero worklist cnt ----
__global__ void splity_kernel(const float* __restrict__ y,
                              unsigned short* __restrict__ yh,
                              unsigned short* __restrict__ yl,
                              int* __restrict__ cnt) {
  if (blockIdx.x == 0 && threadIdx.x == 0) *cnt = 0;
  const int j = blockIdx.x * 2 + (threadIdx.x >> 7);
  const int c = threadIdx.x & 127;
  const float f = y[(size_t)j * ND + c];
  const unsigned short hb = bf16r(f);
  const unsigned short lb = bf16r(f - bf2f(hb));
  yh[(size_t)j * ND + c] = hb;
  yl[(size_t)j * ND + c] = lb;
}

// ---- h[j] = 0.5*||y_j||^2 exact fp32 (k-ascending chain; same as round 4) ----
__global__ void hrow_kernel(const float* __restrict__ y, float* __restrict__ h) {
  const int j = blockIdx.x * blockDim.x + threadIdx.x;
  if (j >= NM) return;
  const float4* __restrict__ yp = (const float4*)(y + (size_t)j * ND);
  float s = 0.f;
#pragma unroll
  for (int u = 0; u < ND / 4; ++u) {
    const float4 v = yp[u];
    s = fmaf(v.x, v.x, s); s = fmaf(v.y, v.y, s);
    s = fmaf(v.z, v.z, s); s = fmaf(v.w, v.w, s);
  }
  h[j] = 0.5f * s;
}

// ---- pass A: MFMA approx distances, per-(q,slice) top-2, no LDS staging ----
#define LOADY(H, L, HV, IT) do {                                               \
    const size_t o_ = (size_t)(IT) * 64 * ND;                                  \
    H[0] = *(const bf16x8*)(ph + o_);                                          \
    H[1] = *(const bf16x8*)(ph + o_ + 32);                                     \
    H[2] = *(const bf16x8*)(ph + o_ + 64);                                     \
    H[3] = *(const bf16x8*)(ph + o_ + 96);                                     \
    L[0] = *(const bf16x8*)(pl + o_);                                          \
    L[1] = *(const bf16x8*)(pl + o_ + 32);                                     \
    L[2] = *(const bf16x8*)(pl + o_ + 64);                                     \
    L[3] = *(const bf16x8*)(pl + o_ + 96);                                     \
    HV = phv[(IT) * 64];                                                       \
  } while (0)

#define COMPY(H, L, HV, IT) do {                                               \
    f32x4 a0 = {0.f, 0.f, 0.f, 0.f}, a1 = {0.f, 0.f, 0.f, 0.f};               \
    __builtin_amdgcn_s_setprio(1);                                             \
    _Pragma("unroll")                                                          \
    for (int ks = 0; ks < 4; ++ks) {                                           \
      a0 = __builtin_amdgcn_mfma_f32_16x16x32_bf16(xh_[0][ks], H[ks], a0, 0, 0, 0); \
      a1 = __builtin_amdgcn_mfma_f32_16x16x32_bf16(xh_[1][ks], H[ks], a1, 0, 0, 0); \
      a0 = __builtin_amdgcn_mfma_f32_16x16x32_bf16(xl_[0][ks], H[ks], a0, 0, 0, 0); \
      a1 = __builtin_amdgcn_mfma_f32_16x16x32_bf16(xl_[1][ks], H[ks], a1, 0, 0, 0); \
      a0 = __builtin_amdgcn_mfma_f32_16x16x32_bf16(xh_[0][ks], L[ks], a0, 0, 0, 0); \
      a1 = __builtin_amdgcn_mfma_f32_16x16x32_bf16(xh_[1][ks], L[ks], a1, 0, 0, 0); \
    }                                                                          \
    __builtin_amdgcn_s_setprio(0);                                             \
    const int jj_ = r0 + (IT) * 64;                                            \
    _Pragma("unroll")                                                          \
    for (int p = 0; p < 8; ++p) {                                              \
      const float s_ = HV - ((p < 4) ? a0[p] : a1[p - 4]);                     \
      const bool lt_ = s_ < v1[p];                                             \
      v2[p] = fminf(v2[p], fmaxf(v1[p], s_));                                  \
      v1[p] = fminf(v1[p], s_);                                                \
      ix[p] = lt_ ? jj_ : ix[p];                                               \
    }                                                                          \
  } while (0)

__global__ __launch_bounds__(BT) void nnA_mfma(
    const float* __restrict__ x, const unsigned short* __restrict__ yh,
    const unsigned short* __restrict__ yl, const float* __restrict__ h,
    float* __restrict__ pv1, int* __restrict__ pi1, float* __restrict__ pv2) {
  __shared__ float rv1[4][QB], rv2[4][QB];
  __shared__ int ri1[4][QB];
  const int t = threadIdx.x, lane = t & 63, w = t >> 6;
  const int l15 = lane & 15, lg = lane >> 4;
  const int slice = blockIdx.x & (NSLICE - 1);
  const int q0 = (blockIdx.x >> 3) * QB;

  // x fragments (hi/lo); A-frag: row=l15 (query), k=lg*8+i
  bf16x8 xh_[2][4], xl_[2][4];
#pragma unroll
  for (int qt = 0; qt < 2; ++qt)
#pragma unroll
    for (int ks = 0; ks < 4; ++ks) {
      const float* xp = x + (size_t)(q0 + qt * 16 + l15) * ND + ks * 32 + lg * 8;
      const float4 f0 = *(const float4*)xp;
      const float4 f1 = *(const float4*)(xp + 4);
      const float ff[8] = {f0.x, f0.y, f0.z, f0.w, f1.x, f1.y, f1.z, f1.w};
      bf16x8 vh, vl;
#pragma unroll
      for (int i = 0; i < 8; ++i) {
        const unsigned short hb = bf16r(ff[i]);
        vh[i] = (short)hb;
        vl[i] = (short)bf16r(ff[i] - bf2f(hb));
      }
      xh_[qt][ks] = vh; xl_[qt][ks] = vl;
    }

  float v1[8], v2[8]; int ix[8];
#pragma unroll
  for (int p = 0; p < 8; ++p) { v1[p] = 3.4e38f; v2[p] = 3.4e38f; ix[p] = 0; }

  // This lane's first y-row; advances 64 rows per iteration (B-frag col = l15).
  const int r0 = slice * SLICE + w * 16 + l15;
  const unsigned short* __restrict__ ph = yh + (size_t)r0 * ND + lg * 8;
  const unsigned short* __restrict__ pl = yl + (size_t)r0 * ND + lg * 8;
  const float* __restrict__ phv = h + r0;

  bf16x8 Ah[4], Al[4], Bh[4], Bl[4];
  float hA, hB;

  LOADY(Ah, Al, hA, 0);
#pragma unroll 1
  for (int s = 0; s < 31; ++s) {
    LOADY(Bh, Bl, hB, 2 * s + 1);
    COMPY(Ah, Al, hA, 2 * s);
    LOADY(Ah, Al, hA, 2 * s + 2);
    COMPY(Bh, Bl, hB, 2 * s + 1);
  }
  LOADY(Bh, Bl, hB, 63);
  COMPY(Ah, Al, hA, 62);
  COMPY(Bh, Bl, hB, 63);

  // reduce across the 16 lanes sharing each query (lanes [16g,16g+15], j=l15)
#pragma unroll
  for (int p = 0; p < 8; ++p) {
    float m1 = v1[p], m2 = v2[p]; int i1 = ix[p];
    for (int off = 1; off < 16; off <<= 1) {
      const float o1 = __shfl_xor(m1, off);
      const float o2 = __shfl_xor(m2, off);
      const int oi = __shfl_xor(i1, off);
      const float n2 = fminf(fmaxf(m1, o1), fminf(m2, o2));
      if (o1 < m1 || (o1 == m1 && oi < i1)) { m1 = o1; i1 = oi; }
      m2 = n2;
    }
    if (l15 == 0) {
      const int ql = (p >> 2) * 16 + lg * 4 + (p & 3);  // D-layout row
      rv1[w][ql] = m1; rv2[w][ql] = m2; ri1[w][ql] = i1;
    }
  }
  __syncthreads();
  if (t < QB) {
    float m1 = rv1[0][t], m2 = rv2[0][t]; int i1 = ri1[0][t];
#pragma unroll
    for (int w2 = 1; w2 < 4; ++w2) {
      const float o1 = rv1[w2][t], o2 = rv2[w2][t];
      const int oi = ri1[w2][t];
      const float n2 = fminf(fmaxf(m1, o1), fminf(m2, o2));
      if (o1 < m1 || (o1 == m1 && oi < i1)) { m1 = o1; i1 = oi; }
      m2 = n2;
    }
    pv1[(size_t)(q0 + t) * NSLICE + slice] = m1;
    pv2[(size_t)(q0 + t) * NSLICE + slice] = m2;
    pi1[(size_t)(q0 + t) * NSLICE + slice] = i1;
  }
}

// exact fp32 key; k-ascending chain (identical in B and C)
__device__ __forceinline__ unsigned long long exact_key(
    const float* __restrict__ x, const float* __restrict__ y,
    const float* __restrict__ h, int q, int j) {
  const float* xp = x + (size_t)q * ND;
  const float* yp = y + (size_t)j * ND;
  float dot = 0.f;
#pragma unroll
  for (int k = 0; k < ND; ++k) dot = fmaf(xp[k], yp[k], dot);
  return packsd(h[j] - dot, j);
}

// ---- pass B: candidate logic ----
__global__ void nnB_kernel(const float* __restrict__ x, const float* __restrict__ y,
                           const float* __restrict__ h, const float* __restrict__ lab,
                           const float* __restrict__ pv1, const int* __restrict__ pi1,
                           const float* __restrict__ pv2, float* __restrict__ out,
                           unsigned long long* __restrict__ packed,
                           int* __restrict__ mode, int* __restrict__ wl,
                           int* __restrict__ cnt) {
  const int q = blockIdx.x * blockDim.x + threadIdx.x;
  if (q >= NQ) return;
  float m = 3.4e38f;
  for (int s = 0; s < NSLICE; ++s) m = fminf(m, pv1[q * NSLICE + s]);
  const float thr = m + EPS;
  int singles[NSLICE], resc[NSLICE], ns = 0, nr = 0;
  for (int s = 0; s < NSLICE; ++s) {
    if (pv1[q * NSLICE + s] <= thr) {
      if (pv2[q * NSLICE + s] <= thr) resc[nr++] = s;
      else singles[ns++] = pi1[q * NSLICE + s];
    }
  }
  if (nr == 0) {
    if (ns == 1) { out[q] = lab[singles[0]]; mode[q] = 0; return; }
    unsigned long long b = ~0ull;
    for (int i = 0; i < ns; ++i) {
      const unsigned long long k = exact_key(x, y, h, q, singles[i]);
      b = k < b ? k : b;
    }
    out[q] = lab[(unsigned)(b & 0xFFFFFFFFull)];
    mode[q] = 0; return;
  }
  const int base = atomicAdd(cnt, nr);
  // write whatever fits (never leave holes below WLCAP; extra scans are harmless)
  for (int i = 0; i < nr; ++i)
    if (base + i < WLCAP) wl[base + i] = (q << 3) | resc[i];
  unsigned long long b = ~0ull;
  for (int i = 0; i < ns; ++i) {
    const unsigned long long k = exact_key(x, y, h, q, singles[i]);
    b = k < b ? k : b;
  }
  if (base + nr <= WLCAP) {
    packed[q] = b; mode[q] = 1;  // pass C fills the rest
  } else {  // overflow (practically impossible): resolve fully serial
    for (int i = 0; i < nr; ++i) {
      const int j0 = resc[i] * SLICE;
      for (int j = j0; j < j0 + SLICE; ++j) {
        const unsigned long long k = exact_key(x, y, h, q, j);
        b = k < b ? k : b;
      }
    }
    out[q] = lab[(unsigned)(b & 0xFFFFFFFFull)]; mode[q] = 0;
  }
}

// ---- pass C: rescan worklist slices, exact fp32, atomicMin ----
__global__ __launch_bounds__(BT) void nnC_kernel(
    const float* __restrict__ x, const float* __restrict__ y,
    const float* __restrict__ h, const int* __restrict__ wl,
    const int* __restrict__ cnt, unsigned long long* __restrict__ packed) {
  __shared__ float xs[ND];
  __shared__ unsigned long long wb[4];
  int n = *cnt; if (n > WLCAP) n = WLCAP;
  const int t = threadIdx.x, lane = t & 63, w = t >> 6;
  for (int e = blockIdx.x; e < n; e += gridDim.x) {
    const int v = wl[e], q = v >> 3, sl = v & 7;
    __syncthreads();
    if (t < ND) xs[t] = x[(size_t)q * ND + t];
    __syncthreads();
    unsigned long long best = ~0ull;
    for (int i = 0; i < SLICE / BT; ++i) {
      const int j = sl * SLICE + i * BT + t;
      const float* yp = y + (size_t)j * ND;
      float dot = 0.f;
#pragma unroll
      for (int k = 0; k < ND; ++k) dot = fmaf(xs[k], yp[k], dot);
      const unsigned long long kk = packsd(h[j] - dot, j);
      if (kk < best) best = kk;
    }
    for (int off = 32; off; off >>= 1) {
      const unsigned long long o = __shfl_xor(best, off);
      if (o < best) best = o;
    }
    if (lane == 0) wb[w] = best;
    __syncthreads();
    if (t == 0) {
      unsigned long long b = wb[0];
      for (int w2 = 1; w2 < 4; ++w2) if (wb[w2] < b) b = wb[w2];
      atomicMin(packed + q, b);
    }
  }
}

// ---- pass D: finalize pending queries ----
__global__ void nnD_kernel(const unsigned long long* __restrict__ packed,
                           const int* __restrict__ mode,
                           const float* __restrict__ lab, float* __restrict__ out) {
  const int q = blockIdx.x * blockDim.x + threadIdx.x;
  if (q >= NQ) return;
  if (mode[q]) out[q] = lab[(unsigned)(packed[q] & 0xFFFFFFFFull)];
}

// ---- fallback (round-2 kernel, known-passing) ----
template <int USE_H>
__global__ __launch_bounds__(BT, 2) void nn_fallback(
    const float* __restrict__ x, const float* __restrict__ y,
    const float* __restrict__ lab, const float* __restrict__ h,
    float* __restrict__ out) {
  const int t = threadIdx.x;
  const int q0 = blockIdx.x * 16;
  float bv[16]; int bi[16];
#pragma unroll
  for (int q = 0; q < 16; ++q) { bv[q] = 3.4e38f; bi[q] = 0; }
  for (int it = 0; it < NM / 512; ++it) {
    const int j0 = it * 512 + t, j1 = j0 + 256;
    const float4* __restrict__ yp0 = (const float4*)(y + (size_t)j0 * ND);
    const float4* __restrict__ yp1 = (const float4*)(y + (size_t)j1 * ND);
    float acc0[16], acc1[16];
#pragma unroll
    for (int q = 0; q < 16; ++q) { acc0[q] = 0.f; acc1[q] = 0.f; }
    float y20 = 0.f, y21 = 0.f;
#pragma unroll 1
    for (int kc = 0; kc < 4; ++kc) {
      float4 a0[8], a1[8];
#pragma unroll
      for (int u = 0; u < 8; ++u) { a0[u] = yp0[kc * 8 + u]; a1[u] = yp1[kc * 8 + u]; }
      if (USE_H == 0) {
#pragma unroll
        for (int u = 0; u < 8; ++u) {
          y20 = fmaf(a0[u].x, a0[u].x, y20); y20 = fmaf(a0[u].y, a0[u].y, y20);
          y20 = fmaf(a0[u].z, a0[u].z, y20); y20 = fmaf(a0[u].w, a0[u].w, y20);
          y21 = fmaf(a1[u].x, a1[u].x, y21); y21 = fmaf(a1[u].y, a1[u].y, y21);
          y21 = fmaf(a1[u].z, a1[u].z, y21); y21 = fmaf(a1[u].w, a1[u].w, y21);
        }
      }
#pragma unroll
      for (int q = 0; q < 16; ++q) {
        const float* __restrict__ xq = x + (size_t)(q0 + q) * ND + kc * 32;
        float s0 = acc0[q], s1 = acc1[q];
#pragma unroll
        for (int u = 0; u < 8; ++u) {
          const float4 xv = *(const float4*)(xq + u * 4);
          s0 = fmaf(a0[u].x, xv.x, s0); s0 = fmaf(a0[u].y, xv.y, s0);
          s0 = fmaf(a0[u].z, xv.z, s0); s0 = fmaf(a0[u].w, xv.w, s0);
          s1 = fmaf(a1[u].x, xv.x, s1); s1 = fmaf(a1[u].y, xv.y, s1);
          s1 = fmaf(a1[u].z, xv.z, s1); s1 = fmaf(a1[u].w, xv.w, s1);
        }
        acc0[q] = s0; acc1[q] = s1;
      }
    }
    float h0, h1;
    if (USE_H) { h0 = h[j0]; h1 = h[j1]; }
    else { h0 = 0.5f * y20; h1 = 0.5f * y21; }
#pragma unroll
    for (int q = 0; q < 16; ++q) {
      const float s0 = h0 - acc0[q], s1 = h1 - acc1[q];
      if (s0 < bv[q]) { bv[q] = s0; bi[q] = j0; }
      if (s1 < bv[q]) { bv[q] = s1; bi[q] = j1; }
    }
  }
  __shared__ float rv[4][16];
  __shared__ int ri[4][16];
  const int lane = t & 63, w = t >> 6;
#pragma unroll
  for (int q = 0; q < 16; ++q) {
    float v = bv[q]; int ixq = bi[q];
    for (int off = 32; off; off >>= 1) {
      const float ov = __shfl_down(v, off);
      const int oi = __shfl_down(ixq, off);
      if (ov < v || (ov == v && oi < ixq)) { v = ov; ixq = oi; }
    }
    if (lane == 0) { rv[w][q] = v; ri[w][q] = ixq; }
  }
  __syncthreads();
  if (t < 16) {
    float v = rv[0][t]; int ixq = ri[0][t];
#pragma unroll
    for (int w2 = 1; w2 < 4; ++w2) {
      const float ov = rv[w2][t]; const int oi = ri[w2][t];
      if (ov < v || (ov == v && oi < ixq)) { v = ov; ixq = oi; }
    }
    out[q0 + t] = lab[ixq];
  }
}

extern "C" void kernel_launch(void* const* d_in, const int* in_sizes, int n_in,
                              void* d_out, int out_size, void* d_ws, size_t ws_size,
                              hipStream_t stream) {
  const float* x = (const float*)d_in[0];
  const float* y = (const float*)d_in[1];
  const float* lab = (const float*)d_in[2];
  float* out = (float*)d_out;

  const size_t o_yh = 0;
  const size_t o_yl = o_yh + (size_t)NM * ND * 2;   // 8 MB
  const size_t o_h  = o_yl + (size_t)NM * ND * 2;   // +8 MB
  const size_t o_p1 = o_h + (size_t)NM * 4;
  const size_t o_p2 = o_p1 + (size_t)NQ * NSLICE * 4;
  const size_t o_i1 = o_p2 + (size_t)NQ * NSLICE * 4;
  const size_t o_pk = o_i1 + (size_t)NQ * NSLICE * 4;
  const size_t o_wl = o_pk + (size_t)NQ * 8;
  const size_t o_md = o_wl + (size_t)WLCAP * 4;
  const size_t o_ct = o_md + (size_t)NQ * 4;
  const size_t need = o_ct + 16;

  if (ws_size >= need) {
    char* W = (char*)d_ws;
    unsigned short* yh = (unsigned short*)(W + o_yh);
    unsigned short* yl = (unsigned short*)(W + o_yl);
    float* h = (float*)(W + o_h);
    float* pv1 = (float*)(W + o_p1);
    float* pv2 = (float*)(W + o_p2);
    int* pi1 = (int*)(W + o_i1);
    unsigned long long* packed = (unsigned long long*)(W + o_pk);
    int* wl = (int*)(W + o_wl);
    int* mode = (int*)(W + o_md);
    int* cnt = (int*)(W + o_ct);
    splity_kernel<<<NM / 2, BT, 0, stream>>>(y, yh, yl, cnt);
    hrow_kernel<<<NM / BT, BT, 0, stream>>>(y, h);
    nnA_mfma<<<(NQ / QB) * NSLICE, BT, 0, stream>>>(x, yh, yl, h, pv1, pi1, pv2);
    nnB_kernel<<<NQ / BT, BT, 0, stream>>>(x, y, h, lab, pv1, pi1, pv2,
                                           out, packed, mode, wl, cnt);
    nnC_kernel<<<256, BT, 0, stream>>>(x, y, h, wl, cnt, packed);
    nnD_kernel<<<NQ / BT, BT, 0, stream>>>(packed, mode, lab, out);
  } else if (ws_size >= (size_t)NM * 4) {
    float* h = (float*)d_ws;
    hrow_kernel<<<NM / BT, BT, 0, stream>>>(y, h);
    nn_fallback<1><<<NQ / 16, BT, 0, stream>>>(x, y, lab, h, out);
  } else {
    nn_fallback<0><<<NQ / 16, BT, 0, stream>>>(x, y, lab, nullptr, out);
  }
}

// Round 6
// 322.763 us; speedup vs baseline: 1.7915x; 1.7915x over previous
//
#include <hip/hip_runtime.h>

// 1-NN via 3-term bf16-split MFMA + provably-safe exact rescore.
// argmin_j ||x_i - y_j||^2 == argmin_j (0.5||y_j||^2 - x_i.y_j).
// Pass A (MFMA): d~ = h_j - (xhi.yhi + xhi.ylo + xlo.yhi), per-(q,slice) top-2 min.
// Pass B: candidates = {j : d~ <= min_q + EPS}; 1 candidate -> done; else exact
// fp32 rescore (serial or slice-rescan worklist) with (dist,idx)-lex atomicMin.
// EPS=0.0625 is >=100x the bf16-split error bound (~5e-4).
//
// Round 6: round 5 was VMEM front-end bound: each B-frag load had 64 lanes
// touching 16 distinct cachelines (row-gather) -> 128 line-events/iter vs 115cyc
// of MFMA. Fix: splity writes y in FRAGMENT-PACKED order ypk[rg][ks][hl][lane][8]
// (lane = lg*16+l15 = the mfma_16x16x32_bf16 B-frag lane map), so every load is
// base + lane*16B: one coalesced 1KB transaction, 8 lines/instr (minimum).
// Numerics identical to round 5 (absmax 0.0). Also: v2 update via v_med3_f32.

#define NQ 8192
#define NM 32768
#define ND 128
#define BT 256
#define NSLICE 8
#define SLICE (NM / NSLICE)   // 4096
#define QB 32                 // queries per block (pass A)
#define EPS 0.0625f
#define WLCAP 16384

using bf16x8 = __attribute__((ext_vector_type(8))) short;
using f32x4  = __attribute__((ext_vector_type(4))) float;

__device__ __forceinline__ unsigned short bf16r(float f) {
  unsigned u = __float_as_uint(f);
  u += 0x7FFFu + ((u >> 16) & 1u);
  return (unsigned short)(u >> 16);
}
__device__ __forceinline__ float bf2f(unsigned short h) {
  return __uint_as_float(((unsigned)h) << 16);
}
__device__ __forceinline__ unsigned long long packsd(float s, int j) {
  unsigned u = __float_as_uint(s);
  u ^= (u & 0x80000000u) ? 0xFFFFFFFFu : 0x80000000u;  // monotone float->uint
  return (((unsigned long long)u) << 32) | (unsigned)j;
}

// ---- split y -> fragment-packed bf16 hi/lo: ypk[rg][ks][hl][lane][8] ----
// rg = j>>4 (16-row group), ks = k-block of 32, hl = 0 hi / 1 lo,
// lane = lg*16 + (j&15) with lg = (c>>3)&3, e = c&7.
__global__ void splity_kernel(const float* __restrict__ y,
                              unsigned short* __restrict__ ypk,
                              int* __restrict__ cnt) {
  if (blockIdx.x == 0 && threadIdx.x == 0) *cnt = 0;
  const int j = blockIdx.x * 2 + (threadIdx.x >> 7);
  const int c = threadIdx.x & 127;
  const float f = y[(size_t)j * ND + c];
  const unsigned short hb = bf16r(f);
  const unsigned short lb = bf16r(f - bf2f(hb));
  const int rg = j >> 4, jl = j & 15;
  const int ks = c >> 5, lg = (c >> 3) & 3, e = c & 7;
  const int lane = lg * 16 + jl;
  const size_t base = (size_t)rg * 4096 + (size_t)ks * 1024 + (size_t)lane * 8 + e;
  ypk[base] = hb;        // hl = 0
  ypk[base + 512] = lb;  // hl = 1
}

// ---- h[j] = 0.5*||y_j||^2 exact fp32 (k-ascending chain; shared with rescore) ----
__global__ void hrow_kernel(const float* __restrict__ y, float* __restrict__ h) {
  const int j = blockIdx.x * blockDim.x + threadIdx.x;
  if (j >= NM) return;
  const float4* __restrict__ yp = (const float4*)(y + (size_t)j * ND);
  float s = 0.f;
#pragma unroll
  for (int u = 0; u < ND / 4; ++u) {
    const float4 v = yp[u];
    s = fmaf(v.x, v.x, s); s = fmaf(v.y, v.y, s);
    s = fmaf(v.z, v.z, s); s = fmaf(v.w, v.w, s);
  }
  h[j] = 0.5f * s;
}

// ---- pass A: MFMA approx distances, per-(q,slice) top-2, packed-coalesced loads ----
#define LOADY(H, L, HV, IT) do {                                               \
    const unsigned short* p_ = pp + (size_t)(IT) * 16384;                      \
    H[0] = *(const bf16x8*)(p_);                                               \
    H[1] = *(const bf16x8*)(p_ + 1024);                                        \
    H[2] = *(const bf16x8*)(p_ + 2048);                                        \
    H[3] = *(const bf16x8*)(p_ + 3072);                                        \
    L[0] = *(const bf16x8*)(p_ + 512);                                         \
    L[1] = *(const bf16x8*)(p_ + 1536);                                        \
    L[2] = *(const bf16x8*)(p_ + 2560);                                        \
    L[3] = *(const bf16x8*)(p_ + 3584);                                        \
    HV = phv[(IT) * 64];                                                       \
  } while (0)

#define COMPY(H, L, HV, IT) do {                                               \
    f32x4 a0 = {0.f, 0.f, 0.f, 0.f}, a1 = {0.f, 0.f, 0.f, 0.f};               \
    __builtin_amdgcn_s_setprio(1);                                             \
    _Pragma("unroll")                                                          \
    for (int ks = 0; ks < 4; ++ks) {                                           \
      a0 = __builtin_amdgcn_mfma_f32_16x16x32_bf16(xh_[0][ks], H[ks], a0, 0, 0, 0); \
      a1 = __builtin_amdgcn_mfma_f32_16x16x32_bf16(xh_[1][ks], H[ks], a1, 0, 0, 0); \
      a0 = __builtin_amdgcn_mfma_f32_16x16x32_bf16(xl_[0][ks], H[ks], a0, 0, 0, 0); \
      a1 = __builtin_amdgcn_mfma_f32_16x16x32_bf16(xl_[1][ks], H[ks], a1, 0, 0, 0); \
      a0 = __builtin_amdgcn_mfma_f32_16x16x32_bf16(xh_[0][ks], L[ks], a0, 0, 0, 0); \
      a1 = __builtin_amdgcn_mfma_f32_16x16x32_bf16(xh_[1][ks], L[ks], a1, 0, 0, 0); \
    }                                                                          \
    __builtin_amdgcn_s_setprio(0);                                             \
    const int jj_ = r0 + (IT) * 64;                                            \
    _Pragma("unroll")                                                          \
    for (int p = 0; p < 8; ++p) {                                              \
      const float s_ = HV - ((p < 4) ? a0[p] : a1[p - 4]);                     \
      const bool lt_ = s_ < v1[p];                                             \
      v2[p] = __builtin_amdgcn_fmed3f(v1[p], v2[p], s_);                       \
      v1[p] = fminf(v1[p], s_);                                                \
      ix[p] = lt_ ? jj_ : ix[p];                                               \
    }                                                                          \
  } while (0)

__global__ __launch_bounds__(BT) void nnA_mfma(
    const float* __restrict__ x, const unsigned short* __restrict__ ypk,
    const float* __restrict__ h,
    float* __restrict__ pv1, int* __restrict__ pi1, float* __restrict__ pv2) {
  __shared__ float rv1[4][QB], rv2[4][QB];
  __shared__ int ri1[4][QB];
  const int t = threadIdx.x, lane = t & 63, w = t >> 6;
  const int l15 = lane & 15, lg = lane >> 4;
  const int slice = blockIdx.x & (NSLICE - 1);
  const int q0 = (blockIdx.x >> 3) * QB;

  // x fragments (hi/lo); A-frag: row=l15 (query), k = ks*32 + lg*8 + i
  bf16x8 xh_[2][4], xl_[2][4];
#pragma unroll
  for (int qt = 0; qt < 2; ++qt)
#pragma unroll
    for (int ks = 0; ks < 4; ++ks) {
      const float* xp = x + (size_t)(q0 + qt * 16 + l15) * ND + ks * 32 + lg * 8;
      const float4 f0 = *(const float4*)xp;
      const float4 f1 = *(const float4*)(xp + 4);
      const float ff[8] = {f0.x, f0.y, f0.z, f0.w, f1.x, f1.y, f1.z, f1.w};
      bf16x8 vh, vl;
#pragma unroll
      for (int i = 0; i < 8; ++i) {
        const unsigned short hb = bf16r(ff[i]);
        vh[i] = (short)hb;
        vl[i] = (short)bf16r(ff[i] - bf2f(hb));
      }
      xh_[qt][ks] = vh; xl_[qt][ks] = vl;
    }

  float v1[8], v2[8]; int ix[8];
#pragma unroll
  for (int p = 0; p < 8; ++p) { v1[p] = 3.4e38f; v2[p] = 3.4e38f; ix[p] = 0; }

  // Wave w's row-group sequence: rg = slice*256 + w + it*4 (16 rows per iter).
  const int r0 = slice * SLICE + w * 16 + l15;
  const unsigned short* __restrict__ pp =
      ypk + (size_t)(slice * 256 + w) * 4096 + (size_t)lane * 8;
  const float* __restrict__ phv = h + r0;

  bf16x8 Ah[4], Al[4], Bh[4], Bl[4];
  float hA, hB;

  LOADY(Ah, Al, hA, 0);
#pragma unroll 1
  for (int s = 0; s < 31; ++s) {
    LOADY(Bh, Bl, hB, 2 * s + 1);
    COMPY(Ah, Al, hA, 2 * s);
    LOADY(Ah, Al, hA, 2 * s + 2);
    COMPY(Bh, Bl, hB, 2 * s + 1);
  }
  LOADY(Bh, Bl, hB, 63);
  COMPY(Ah, Al, hA, 62);
  COMPY(Bh, Bl, hB, 63);

  // reduce across the 16 lanes sharing each query (lanes [16g,16g+15], j=l15)
#pragma unroll
  for (int p = 0; p < 8; ++p) {
    float m1 = v1[p], m2 = v2[p]; int i1 = ix[p];
    for (int off = 1; off < 16; off <<= 1) {
      const float o1 = __shfl_xor(m1, off);
      const float o2 = __shfl_xor(m2, off);
      const int oi = __shfl_xor(i1, off);
      const float n2 = fminf(fmaxf(m1, o1), fminf(m2, o2));
      if (o1 < m1 || (o1 == m1 && oi < i1)) { m1 = o1; i1 = oi; }
      m2 = n2;
    }
    if (l15 == 0) {
      const int ql = (p >> 2) * 16 + lg * 4 + (p & 3);  // D-layout row
      rv1[w][ql] = m1; rv2[w][ql] = m2; ri1[w][ql] = i1;
    }
  }
  __syncthreads();
  if (t < QB) {
    float m1 = rv1[0][t], m2 = rv2[0][t]; int i1 = ri1[0][t];
#pragma unroll
    for (int w2 = 1; w2 < 4; ++w2) {
      const float o1 = rv1[w2][t], o2 = rv2[w2][t];
      const int oi = ri1[w2][t];
      const float n2 = fminf(fmaxf(m1, o1), fminf(m2, o2));
      if (o1 < m1 || (o1 == m1 && oi < i1)) { m1 = o1; i1 = oi; }
      m2 = n2;
    }
    pv1[(size_t)(q0 + t) * NSLICE + slice] = m1;
    pv2[(size_t)(q0 + t) * NSLICE + slice] = m2;
    pi1[(size_t)(q0 + t) * NSLICE + slice] = i1;
  }
}

// exact fp32 key; k-ascending chain (identical in B and C)
__device__ __forceinline__ unsigned long long exact_key(
    const float* __restrict__ x, const float* __restrict__ y,
    const float* __restrict__ h, int q, int j) {
  const float* xp = x + (size_t)q * ND;
  const float* yp = y + (size_t)j * ND;
  float dot = 0.f;
#pragma unroll
  for (int k = 0; k < ND; ++k) dot = fmaf(xp[k], yp[k], dot);
  return packsd(h[j] - dot, j);
}

// ---- pass B: candidate logic ----
__global__ void nnB_kernel(const float* __restrict__ x, const float* __restrict__ y,
                           const float* __restrict__ h, const float* __restrict__ lab,
                           const float* __restrict__ pv1, const int* __restrict__ pi1,
                           const float* __restrict__ pv2, float* __restrict__ out,
                           unsigned long long* __restrict__ packed,
                           int* __restrict__ mode, int* __restrict__ wl,
                           int* __restrict__ cnt) {
  const int q = blockIdx.x * blockDim.x + threadIdx.x;
  if (q >= NQ) return;
  float m = 3.4e38f;
  for (int s = 0; s < NSLICE; ++s) m = fminf(m, pv1[q * NSLICE + s]);
  const float thr = m + EPS;
  int singles[NSLICE], resc[NSLICE], ns = 0, nr = 0;
  for (int s = 0; s < NSLICE; ++s) {
    if (pv1[q * NSLICE + s] <= thr) {
      if (pv2[q * NSLICE + s] <= thr) resc[nr++] = s;
      else singles[ns++] = pi1[q * NSLICE + s];
    }
  }
  if (nr == 0) {
    if (ns == 1) { out[q] = lab[singles[0]]; mode[q] = 0; return; }
    unsigned long long b = ~0ull;
    for (int i = 0; i < ns; ++i) {
      const unsigned long long k = exact_key(x, y, h, q, singles[i]);
      b = k < b ? k : b;
    }
    out[q] = lab[(unsigned)(b & 0xFFFFFFFFull)];
    mode[q] = 0; return;
  }
  const int base = atomicAdd(cnt, nr);
  // write whatever fits (never leave holes below WLCAP; extra scans are harmless)
  for (int i = 0; i < nr; ++i)
    if (base + i < WLCAP) wl[base + i] = (q << 3) | resc[i];
  unsigned long long b = ~0ull;
  for (int i = 0; i < ns; ++i) {
    const unsigned long long k = exact_key(x, y, h, q, singles[i]);
    b = k < b ? k : b;
  }
  if (base + nr <= WLCAP) {
    packed[q] = b; mode[q] = 1;  // pass C fills the rest
  } else {  // overflow (practically impossible): resolve fully serial
    for (int i = 0; i < nr; ++i) {
      const int j0 = resc[i] * SLICE;
      for (int j = j0; j < j0 + SLICE; ++j) {
        const unsigned long long k = exact_key(x, y, h, q, j);
        b = k < b ? k : b;
      }
    }
    out[q] = lab[(unsigned)(b & 0xFFFFFFFFull)]; mode[q] = 0;
  }
}

// ---- pass C: rescan worklist slices, exact fp32, atomicMin ----
__global__ __launch_bounds__(BT) void nnC_kernel(
    const float* __restrict__ x, const float* __restrict__ y,
    const float* __restrict__ h, const int* __restrict__ wl,
    const int* __restrict__ cnt, unsigned long long* __restrict__ packed) {
  __shared__ float xs[ND];
  __shared__ unsigned long long wb[4];
  int n = *cnt; if (n > WLCAP) n = WLCAP;
  const int t = threadIdx.x, lane = t & 63, w = t >> 6;
  for (int e = blockIdx.x; e < n; e += gridDim.x) {
    const int v = wl[e], q = v >> 3, sl = v & 7;
    __syncthreads();
    if (t < ND) xs[t] = x[(size_t)q * ND + t];
    __syncthreads();
    unsigned long long best = ~0ull;
    for (int i = 0; i < SLICE / BT; ++i) {
      const int j = sl * SLICE + i * BT + t;
      const float* yp = y + (size_t)j * ND;
      float dot = 0.f;
#pragma unroll
      for (int k = 0; k < ND; ++k) dot = fmaf(xs[k], yp[k], dot);
      const unsigned long long kk = packsd(h[j] - dot, j);
      if (kk < best) best = kk;
    }
    for (int off = 32; off; off >>= 1) {
      const unsigned long long o = __shfl_xor(best, off);
      if (o < best) best = o;
    }
    if (lane == 0) wb[w] = best;
    __syncthreads();
    if (t == 0) {
      unsigned long long b = wb[0];
      for (int w2 = 1; w2 < 4; ++w2) if (wb[w2] < b) b = wb[w2];
      atomicMin(packed + q, b);
    }
  }
}

// ---- pass D: finalize pending queries ----
__global__ void nnD_kernel(const unsigned long long* __restrict__ packed,
                           const int* __restrict__ mode,
                           const float* __restrict__ lab, float* __restrict__ out) {
  const int q = blockIdx.x * blockDim.x + threadIdx.x;
  if (q >= NQ) return;
  if (mode[q]) out[q] = lab[(unsigned)(packed[q] & 0xFFFFFFFFull)];
}

// ---- fallback (round-2 kernel, known-passing) ----
template <int USE_H>
__global__ __launch_bounds__(BT, 2) void nn_fallback(
    const float* __restrict__ x, const float* __restrict__ y,
    const float* __restrict__ lab, const float* __restrict__ h,
    float* __restrict__ out) {
  const int t = threadIdx.x;
  const int q0 = blockIdx.x * 16;
  float bv[16]; int bi[16];
#pragma unroll
  for (int q = 0; q < 16; ++q) { bv[q] = 3.4e38f; bi[q] = 0; }
  for (int it = 0; it < NM / 512; ++it) {
    const int j0 = it * 512 + t, j1 = j0 + 256;
    const float4* __restrict__ yp0 = (const float4*)(y + (size_t)j0 * ND);
    const float4* __restrict__ yp1 = (const float4*)(y + (size_t)j1 * ND);
    float acc0[16], acc1[16];
#pragma unroll
    for (int q = 0; q < 16; ++q) { acc0[q] = 0.f; acc1[q] = 0.f; }
    float y20 = 0.f, y21 = 0.f;
#pragma unroll 1
    for (int kc = 0; kc < 4; ++kc) {
      float4 a0[8], a1[8];
#pragma unroll
      for (int u = 0; u < 8; ++u) { a0[u] = yp0[kc * 8 + u]; a1[u] = yp1[kc * 8 + u]; }
      if (USE_H == 0) {
#pragma unroll
        for (int u = 0; u < 8; ++u) {
          y20 = fmaf(a0[u].x, a0[u].x, y20); y20 = fmaf(a0[u].y, a0[u].y, y20);
          y20 = fmaf(a0[u].z, a0[u].z, y20); y20 = fmaf(a0[u].w, a0[u].w, y20);
          y21 = fmaf(a1[u].x, a1[u].x, y21); y21 = fmaf(a1[u].y, a1[u].y, y21);
          y21 = fmaf(a1[u].z, a1[u].z, y21); y21 = fmaf(a1[u].w, a1[u].w, y21);
        }
      }
#pragma unroll
      for (int q = 0; q < 16; ++q) {
        const float* __restrict__ xq = x + (size_t)(q0 + q) * ND + kc * 32;
        float s0 = acc0[q], s1 = acc1[q];
#pragma unroll
        for (int u = 0; u < 8; ++u) {
          const float4 xv = *(const float4*)(xq + u * 4);
          s0 = fmaf(a0[u].x, xv.x, s0); s0 = fmaf(a0[u].y, xv.y, s0);
          s0 = fmaf(a0[u].z, xv.z, s0); s0 = fmaf(a0[u].w, xv.w, s0);
          s1 = fmaf(a1[u].x, xv.x, s1); s1 = fmaf(a1[u].y, xv.y, s1);
          s1 = fmaf(a1[u].z, xv.z, s1); s1 = fmaf(a1[u].w, xv.w, s1);
        }
        acc0[q] = s0; acc1[q] = s1;
      }
    }
    float h0, h1;
    if (USE_H) { h0 = h[j0]; h1 = h[j1]; }
    else { h0 = 0.5f * y20; h1 = 0.5f * y21; }
#pragma unroll
    for (int q = 0; q < 16; ++q) {
      const float s0 = h0 - acc0[q], s1 = h1 - acc1[q];
      if (s0 < bv[q]) { bv[q] = s0; bi[q] = j0; }
      if (s1 < bv[q]) { bv[q] = s1; bi[q] = j1; }
    }
  }
  __shared__ float rv[4][16];
  __shared__ int ri[4][16];
  const int lane = t & 63, w = t >> 6;
#pragma unroll
  for (int q = 0; q < 16; ++q) {
    float v = bv[q]; int ixq = bi[q];
    for (int off = 32; off; off >>= 1) {
      const float ov = __shfl_down(v, off);
      const int oi = __shfl_down(ixq, off);
      if (ov < v || (ov == v && oi < ixq)) { v = ov; ixq = oi; }
    }
    if (lane == 0) { rv[w][q] = v; ri[w][q] = ixq; }
  }
  __syncthreads();
  if (t < 16) {
    float v = rv[0][t]; int ixq = ri[0][t];
#pragma unroll
    for (int w2 = 1; w2 < 4; ++w2) {
      const float ov = rv[w2][t]; const int oi = ri[w2][t];
      if (ov < v || (ov == v && oi < ixq)) { v = ov; ixq = oi; }
    }
    out[q0 + t] = lab[ixq];
  }
}

extern "C" void kernel_launch(void* const* d_in, const int* in_sizes, int n_in,
                              void* d_out, int out_size, void* d_ws, size_t ws_size,
                              hipStream_t stream) {
  const float* x = (const float*)d_in[0];
  const float* y = (const float*)d_in[1];
  const float* lab = (const float*)d_in[2];
  float* out = (float*)d_out;

  const size_t o_ypk = 0;
  const size_t o_h  = o_ypk + (size_t)NM * ND * 4;  // 16 MB packed hi+lo
  const size_t o_p1 = o_h + (size_t)NM * 4;
  const size_t o_p2 = o_p1 + (size_t)NQ * NSLICE * 4;
  const size_t o_i1 = o_p2 + (size_t)NQ * NSLICE * 4;
  const size_t o_pk = o_i1 + (size_t)NQ * NSLICE * 4;
  const size_t o_wl = o_pk + (size_t)NQ * 8;
  const size_t o_md = o_wl + (size_t)WLCAP * 4;
  const size_t o_ct = o_md + (size_t)NQ * 4;
  const size_t need = o_ct + 16;

  if (ws_size >= need) {
    char* W = (char*)d_ws;
    unsigned short* ypk = (unsigned short*)(W + o_ypk);
    float* h = (float*)(W + o_h);
    float* pv1 = (float*)(W + o_p1);
    float* pv2 = (float*)(W + o_p2);
    int* pi1 = (int*)(W + o_i1);
    unsigned long long* packed = (unsigned long long*)(W + o_pk);
    int* wl = (int*)(W + o_wl);
    int* mode = (int*)(W + o_md);
    int* cnt = (int*)(W + o_ct);
    splity_kernel<<<NM / 2, BT, 0, stream>>>(y, ypk, cnt);
    hrow_kernel<<<NM / BT, BT, 0, stream>>>(y, h);
    nnA_mfma<<<(NQ / QB) * NSLICE, BT, 0, stream>>>(x, ypk, h, pv1, pi1, pv2);
    nnB_kernel<<<NQ / BT, BT, 0, stream>>>(x, y, h, lab, pv1, pi1, pv2,
                                           out, packed, mode, wl, cnt);
    nnC_kernel<<<256, BT, 0, stream>>>(x, y, h, wl, cnt, packed);
    nnD_kernel<<<NQ / BT, BT, 0, stream>>>(packed, mode, lab, out);
  } else if (ws_size >= (size_t)NM * 4) {
    float* h = (float*)d_ws;
    hrow_kernel<<<NM / BT, BT, 0, stream>>>(y, h);
    nn_fallback<1><<<NQ / 16, BT, 0, stream>>>(x, y, lab, h, out);
  } else {
    nn_fallback<0><<<NQ / 16, BT, 0, stream>>>(x, y, lab, nullptr, out);
  }
}

// Round 8
// 284.150 us; speedup vs baseline: 2.0350x; 1.1359x over previous
//
#include <hip/hip_runtime.h>

// 1-NN via 3-term bf16-split MFMA + provably-safe exact rescore.
// argmin_j ||x_i - y_j||^2 == argmin_j (0.5||y_j||^2 - x_i.y_j).
// Pass A (MFMA): d~ = h_j - (xhi.yhi + xhi.ylo + xlo.yhi), per-(q,slice) top-2 min.
// Pass B: candidates = {j : d~ <= min_q + EPS}; 1 candidate -> done; else exact
// fp32 rescore (serial or slice-rescan worklist) with (dist,idx)-lex atomicMin.
//
// Round 8: round 7's only defect was an operand TYPO in MFST term 6
// (a1 += xl_[0]*FL instead of xh_[1]*FL), which dropped the xhi.ylo term for
// each wave's queries 16-31 -> d~ error ~0.05 > EPS -> one flipped argmin
// (absmax 0.0234). Fixed; MFMA sequence now matches round 6's passing kernel
// exactly. Structure (shared LDS chunk, 4x cross-wave reuse) unchanged.

#define NQ 8192
#define NM 32768
#define ND 128
#define BT 256
#define NSLICE 8
#define SLICE (NM / NSLICE)   // 4096 rows -> 64 chunks of 64
#define QB 128                // queries per block (32 per wave)
#define EPS 0.0625f
#define WLCAP 16384

using bf16x8 = __attribute__((ext_vector_type(8))) short;
using f32x4  = __attribute__((ext_vector_type(4))) float;

__device__ __forceinline__ unsigned short bf16r(float f) {
  unsigned u = __float_as_uint(f);
  u += 0x7FFFu + ((u >> 16) & 1u);
  return (unsigned short)(u >> 16);
}
__device__ __forceinline__ float bf2f(unsigned short h) {
  return __uint_as_float(((unsigned)h) << 16);
}
__device__ __forceinline__ unsigned long long packsd(float s, int j) {
  unsigned u = __float_as_uint(s);
  u ^= (u & 0x80000000u) ? 0xFFFFFFFFu : 0x80000000u;  // monotone float->uint
  return (((unsigned long long)u) << 32) | (unsigned)j;
}
__device__ __forceinline__ void gload_lds16(const void* g, void* l) {
  __builtin_amdgcn_global_load_lds(
      (const __attribute__((address_space(1))) void*)g,
      (__attribute__((address_space(3))) void*)l, 16, 0, 0);
}

// ---- split y -> fragment-packed bf16 hi/lo: ypk[rg][ks][hl][lane][8] ----
// rg = j>>4 (16-row group), ks = k-block of 32, hl = 0 hi / 1 lo,
// lane = lg*16 + (j&15) with lg = (c>>3)&3, e = c&7.
__global__ void splity_kernel(const float* __restrict__ y,
                              unsigned short* __restrict__ ypk,
                              int* __restrict__ cnt) {
  if (blockIdx.x == 0 && threadIdx.x == 0) *cnt = 0;
  const int j = blockIdx.x * 2 + (threadIdx.x >> 7);
  const int c = threadIdx.x & 127;
  const float f = y[(size_t)j * ND + c];
  const unsigned short hb = bf16r(f);
  const unsigned short lb = bf16r(f - bf2f(hb));
  const int rg = j >> 4, jl = j & 15;
  const int ks = c >> 5, lg = (c >> 3) & 3, e = c & 7;
  const int lane = lg * 16 + jl;
  const size_t base = (size_t)rg * 4096 + (size_t)ks * 1024 + (size_t)lane * 8 + e;
  ypk[base] = hb;        // hl = 0
  ypk[base + 512] = lb;  // hl = 1
}

// ---- h[j] = 0.5*||y_j||^2 exact fp32 (k-ascending chain; shared with rescore) ----
__global__ void hrow_kernel(const float* __restrict__ y, float* __restrict__ h) {
  const int j = blockIdx.x * blockDim.x + threadIdx.x;
  if (j >= NM) return;
  const float4* __restrict__ yp = (const float4*)(y + (size_t)j * ND);
  float s = 0.f;
#pragma unroll
  for (int u = 0; u < ND / 4; ++u) {
    const float4 v = yp[u];
    s = fmaf(v.x, v.x, s); s = fmaf(v.y, v.y, s);
    s = fmaf(v.z, v.z, s); s = fmaf(v.w, v.w, s);
  }
  h[j] = 0.5f * s;
}

// ---- pass A: shared-LDS-chunk MFMA, per-(q,slice) top-2 ----
// LDS chunk layout (shorts): [rg(4)][ks(4)][hl(2)][lane(64)][8]  = 16384 shorts.
#define LDFR(FH, FL, ST) do {                                                  \
    _Pragma("unroll")                                                          \
    for (int ks = 0; ks < 4; ++ks) {                                           \
      FH[ks] = *(const bf16x8*)&bufc[(ST) * 4096 + ks * 1024 + lane * 8];      \
      FL[ks] = *(const bf16x8*)&bufc[(ST) * 4096 + ks * 1024 + 512 + lane * 8];\
    }                                                                          \
  } while (0)

#define MFST(FH, FL, ST) do {                                                  \
    f32x4 a0 = {0.f, 0.f, 0.f, 0.f}, a1 = {0.f, 0.f, 0.f, 0.f};               \
    __builtin_amdgcn_s_setprio(1);                                             \
    _Pragma("unroll")                                                          \
    for (int ks = 0; ks < 4; ++ks) {                                           \
      a0 = __builtin_amdgcn_mfma_f32_16x16x32_bf16(xh_[0][ks], FH[ks], a0, 0, 0, 0); \
      a1 = __builtin_amdgcn_mfma_f32_16x16x32_bf16(xh_[1][ks], FH[ks], a1, 0, 0, 0); \
      a0 = __builtin_amdgcn_mfma_f32_16x16x32_bf16(xl_[0][ks], FH[ks], a0, 0, 0, 0); \
      a1 = __builtin_amdgcn_mfma_f32_16x16x32_bf16(xl_[1][ks], FH[ks], a1, 0, 0, 0); \
      a0 = __builtin_amdgcn_mfma_f32_16x16x32_bf16(xh_[0][ks], FL[ks], a0, 0, 0, 0); \
      a1 = __builtin_amdgcn_mfma_f32_16x16x32_bf16(xh_[1][ks], FL[ks], a1, 0, 0, 0); \
    }                                                                          \
    __builtin_amdgcn_s_setprio(0);                                             \
    const int jj_ = jb + (ST) * 16 + l15;                                      \
    const float hv_ = hv[ST];                                                  \
    _Pragma("unroll")                                                          \
    for (int p = 0; p < 8; ++p) {                                              \
      const float s_ = hv_ - ((p < 4) ? a0[p] : a1[p - 4]);                    \
      const bool lt_ = s_ < v1[p];                                             \
      v2[p] = __builtin_amdgcn_fmed3f(v1[p], v2[p], s_);                       \
      v1[p] = fminf(v1[p], s_);                                                \
      ix[p] = lt_ ? jj_ : ix[p];                                               \
    }                                                                          \
  } while (0)

__global__ __launch_bounds__(BT, 2) void nnA_mfma(
    const float* __restrict__ x, const unsigned short* __restrict__ ypk,
    const float* __restrict__ h,
    float* __restrict__ pv1, int* __restrict__ pi1, float* __restrict__ pv2) {
  __shared__ unsigned short yl2[2][16384];  // double-buffered 64-row chunk
  const int t = threadIdx.x, lane = t & 63, w = t >> 6;
  const int l15 = lane & 15, lg = lane >> 4;
  const int slice = blockIdx.x & (NSLICE - 1);
  const int q0 = (blockIdx.x >> 3) * QB + w * 32;  // this wave's 32 queries

  // x fragments (hi/lo); A-frag: row=l15 (query), k = ks*32 + lg*8 + i
  bf16x8 xh_[2][4], xl_[2][4];
#pragma unroll
  for (int qt = 0; qt < 2; ++qt)
#pragma unroll
    for (int ks = 0; ks < 4; ++ks) {
      const float* xp = x + (size_t)(q0 + qt * 16 + l15) * ND + ks * 32 + lg * 8;
      const float4 f0 = *(const float4*)xp;
      const float4 f1 = *(const float4*)(xp + 4);
      const float ff[8] = {f0.x, f0.y, f0.z, f0.w, f1.x, f1.y, f1.z, f1.w};
      bf16x8 vh, vl;
#pragma unroll
      for (int i = 0; i < 8; ++i) {
        const unsigned short hb = bf16r(ff[i]);
        vh[i] = (short)hb;
        vl[i] = (short)bf16r(ff[i] - bf2f(hb));
      }
      xh_[qt][ks] = vh; xl_[qt][ks] = vl;
    }

  float v1[8], v2[8]; int ix[8];
#pragma unroll
  for (int p = 0; p < 8; ++p) { v1[p] = 3.4e38f; v2[p] = 3.4e38f; ix[p] = 0; }

  // Slice base in ypk (shorts): each chunk = 16384 shorts (64 rows).
  const size_t sbase = (size_t)slice * (SLICE / 16) * 4096;

  // Prologue: stage chunk 0 into buf 0. Wave w stages row-group w (8 x 1KB).
  {
    const unsigned short* src = ypk + sbase + w * 4096 + lane * 8;
#pragma unroll
    for (int s = 0; s < 8; ++s)
      gload_lds16(src + s * 512, &yl2[0][w * 4096 + s * 512]);
  }
  __syncthreads();

#pragma unroll 1
  for (int it = 0; it < SLICE / 64; ++it) {
    const int cur = it & 1;
    // Stage next chunk into the other buffer (drained by iter-end barrier).
    if (it < SLICE / 64 - 1) {
      const unsigned short* src =
          ypk + sbase + (size_t)(it + 1) * 16384 + w * 4096 + lane * 8;
      unsigned short* dst = &yl2[cur ^ 1][w * 4096];
#pragma unroll
      for (int s = 0; s < 8; ++s)
        gload_lds16(src + s * 512, dst + s * 512);
    }
    const int jb = slice * SLICE + it * 64;
    float hv[4];
#pragma unroll
    for (int st = 0; st < 4; ++st) hv[st] = h[jb + st * 16 + l15];

    const unsigned short* __restrict__ bufc = &yl2[cur][0];
    bf16x8 FAh[4], FAl[4], FBh[4], FBl[4];
    LDFR(FAh, FAl, 0);
    LDFR(FBh, FBl, 1);
    MFST(FAh, FAl, 0);
    LDFR(FAh, FAl, 2);
    MFST(FBh, FBl, 1);
    LDFR(FBh, FBl, 3);
    MFST(FAh, FAl, 2);
    MFST(FBh, FBl, 3);
    __syncthreads();
  }

  // Reduce across the 16 lanes sharing each query; waves own disjoint queries.
#pragma unroll
  for (int p = 0; p < 8; ++p) {
    float m1 = v1[p], m2 = v2[p]; int i1 = ix[p];
    for (int off = 1; off < 16; off <<= 1) {
      const float o1 = __shfl_xor(m1, off);
      const float o2 = __shfl_xor(m2, off);
      const int oi = __shfl_xor(i1, off);
      const float n2 = fminf(fmaxf(m1, o1), fminf(m2, o2));
      if (o1 < m1 || (o1 == m1 && oi < i1)) { m1 = o1; i1 = oi; }
      m2 = n2;
    }
    if (l15 == 0) {
      const int q = q0 + (p >> 2) * 16 + lg * 4 + (p & 3);  // D-layout row
      pv1[(size_t)q * NSLICE + slice] = m1;
      pv2[(size_t)q * NSLICE + slice] = m2;
      pi1[(size_t)q * NSLICE + slice] = i1;
    }
  }
}

// exact fp32 key; k-ascending chain (identical in B and C)
__device__ __forceinline__ unsigned long long exact_key(
    const float* __restrict__ x, const float* __restrict__ y,
    const float* __restrict__ h, int q, int j) {
  const float* xp = x + (size_t)q * ND;
  const float* yp = y + (size_t)j * ND;
  float dot = 0.f;
#pragma unroll
  for (int k = 0; k < ND; ++k) dot = fmaf(xp[k], yp[k], dot);
  return packsd(h[j] - dot, j);
}

// ---- pass B: candidate logic ----
__global__ void nnB_kernel(const float* __restrict__ x, const float* __restrict__ y,
                           const float* __restrict__ h, const float* __restrict__ lab,
                           const float* __restrict__ pv1, const int* __restrict__ pi1,
                           const float* __restrict__ pv2, float* __restrict__ out,
                           unsigned long long* __restrict__ packed,
                           int* __restrict__ mode, int* __restrict__ wl,
                           int* __restrict__ cnt) {
  const int q = blockIdx.x * blockDim.x + threadIdx.x;
  if (q >= NQ) return;
  float m = 3.4e38f;
  for (int s = 0; s < NSLICE; ++s) m = fminf(m, pv1[q * NSLICE + s]);
  const float thr = m + EPS;
  int singles[NSLICE], resc[NSLICE], ns = 0, nr = 0;
  for (int s = 0; s < NSLICE; ++s) {
    if (pv1[q * NSLICE + s] <= thr) {
      if (pv2[q * NSLICE + s] <= thr) resc[nr++] = s;
      else singles[ns++] = pi1[q * NSLICE + s];
    }
  }
  if (nr == 0) {
    if (ns == 1) { out[q] = lab[singles[0]]; mode[q] = 0; return; }
    unsigned long long b = ~0ull;
    for (int i = 0; i < ns; ++i) {
      const unsigned long long k = exact_key(x, y, h, q, singles[i]);
      b = k < b ? k : b;
    }
    out[q] = lab[(unsigned)(b & 0xFFFFFFFFull)];
    mode[q] = 0; return;
  }
  const int base = atomicAdd(cnt, nr);
  // write whatever fits (never leave holes below WLCAP; extra scans are harmless)
  for (int i = 0; i < nr; ++i)
    if (base + i < WLCAP) wl[base + i] = (q << 3) | resc[i];
  unsigned long long b = ~0ull;
  for (int i = 0; i < ns; ++i) {
    const unsigned long long k = exact_key(x, y, h, q, singles[i]);
    b = k < b ? k : b;
  }
  if (base + nr <= WLCAP) {
    packed[q] = b; mode[q] = 1;  // pass C fills the rest
  } else {  // overflow (practically impossible): resolve fully serial
    for (int i = 0; i < nr; ++i) {
      const int j0 = resc[i] * SLICE;
      for (int j = j0; j < j0 + SLICE; ++j) {
        const unsigned long long k = exact_key(x, y, h, q, j);
        b = k < b ? k : b;
      }
    }
    out[q] = lab[(unsigned)(b & 0xFFFFFFFFull)]; mode[q] = 0;
  }
}

// ---- pass C: rescan worklist slices, exact fp32, atomicMin ----
__global__ __launch_bounds__(BT) void nnC_kernel(
    const float* __restrict__ x, const float* __restrict__ y,
    const float* __restrict__ h, const int* __restrict__ wl,
    const int* __restrict__ cnt, unsigned long long* __restrict__ packed) {
  __shared__ float xs[ND];
  __shared__ unsigned long long wb[4];
  int n = *cnt; if (n > WLCAP) n = WLCAP;
  const int t = threadIdx.x, lane = t & 63, w = t >> 6;
  for (int e = blockIdx.x; e < n; e += gridDim.x) {
    const int v = wl[e], q = v >> 3, sl = v & 7;
    __syncthreads();
    if (t < ND) xs[t] = x[(size_t)q * ND + t];
    __syncthreads();
    unsigned long long best = ~0ull;
    for (int i = 0; i < SLICE / BT; ++i) {
      const int j = sl * SLICE + i * BT + t;
      const float* yp = y + (size_t)j * ND;
      float dot = 0.f;
#pragma unroll
      for (int k = 0; k < ND; ++k) dot = fmaf(xs[k], yp[k], dot);
      const unsigned long long kk = packsd(h[j] - dot, j);
      if (kk < best) best = kk;
    }
    for (int off = 32; off; off >>= 1) {
      const unsigned long long o = __shfl_xor(best, off);
      if (o < best) best = o;
    }
    if (lane == 0) wb[w] = best;
    __syncthreads();
    if (t == 0) {
      unsigned long long b = wb[0];
      for (int w2 = 1; w2 < 4; ++w2) if (wb[w2] < b) b = wb[w2];
      atomicMin(packed + q, b);
    }
  }
}

// ---- pass D: finalize pending queries ----
__global__ void nnD_kernel(const unsigned long long* __restrict__ packed,
                           const int* __restrict__ mode,
                           const float* __restrict__ lab, float* __restrict__ out) {
  const int q = blockIdx.x * blockDim.x + threadIdx.x;
  if (q >= NQ) return;
  if (mode[q]) out[q] = lab[(unsigned)(packed[q] & 0xFFFFFFFFull)];
}

// ---- fallback (round-2 kernel, known-passing) ----
template <int USE_H>
__global__ __launch_bounds__(BT, 2) void nn_fallback(
    const float* __restrict__ x, const float* __restrict__ y,
    const float* __restrict__ lab, const float* __restrict__ h,
    float* __restrict__ out) {
  const int t = threadIdx.x;
  const int q0 = blockIdx.x * 16;
  float bv[16]; int bi[16];
#pragma unroll
  for (int q = 0; q < 16; ++q) { bv[q] = 3.4e38f; bi[q] = 0; }
  for (int it = 0; it < NM / 512; ++it) {
    const int j0 = it * 512 + t, j1 = j0 + 256;
    const float4* __restrict__ yp0 = (const float4*)(y + (size_t)j0 * ND);
    const float4* __restrict__ yp1 = (const float4*)(y + (size_t)j1 * ND);
    float acc0[16], acc1[16];
#pragma unroll
    for (int q = 0; q < 16; ++q) { acc0[q] = 0.f; acc1[q] = 0.f; }
    float y20 = 0.f, y21 = 0.f;
#pragma unroll 1
    for (int kc = 0; kc < 4; ++kc) {
      float4 a0[8], a1[8];
#pragma unroll
      for (int u = 0; u < 8; ++u) { a0[u] = yp0[kc * 8 + u]; a1[u] = yp1[kc * 8 + u]; }
      if (USE_H == 0) {
#pragma unroll
        for (int u = 0; u < 8; ++u) {
          y20 = fmaf(a0[u].x, a0[u].x, y20); y20 = fmaf(a0[u].y, a0[u].y, y20);
          y20 = fmaf(a0[u].z, a0[u].z, y20); y20 = fmaf(a0[u].w, a0[u].w, y20);
          y21 = fmaf(a1[u].x, a1[u].x, y21); y21 = fmaf(a1[u].y, a1[u].y, y21);
          y21 = fmaf(a1[u].z, a1[u].z, y21); y21 = fmaf(a1[u].w, a1[u].w, y21);
        }
      }
#pragma unroll
      for (int q = 0; q < 16; ++q) {
        const float* __restrict__ xq = x + (size_t)(q0 + q) * ND + kc * 32;
        float s0 = acc0[q], s1 = acc1[q];
#pragma unroll
        for (int u = 0; u < 8; ++u) {
          const float4 xv = *(const float4*)(xq + u * 4);
          s0 = fmaf(a0[u].x, xv.x, s0); s0 = fmaf(a0[u].y, xv.y, s0);
          s0 = fmaf(a0[u].z, xv.z, s0); s0 = fmaf(a0[u].w, xv.w, s0);
          s1 = fmaf(a1[u].x, xv.x, s1); s1 = fmaf(a1[u].y, xv.y, s1);
          s1 = fmaf(a1[u].z, xv.z, s1); s1 = fmaf(a1[u].w, xv.w, s1);
        }
        acc0[q] = s0; acc1[q] = s1;
      }
    }
    float h0, h1;
    if (USE_H) { h0 = h[j0]; h1 = h[j1]; }
    else { h0 = 0.5f * y20; h1 = 0.5f * y21; }
#pragma unroll
    for (int q = 0; q < 16; ++q) {
      const float s0 = h0 - acc0[q], s1 = h1 - acc1[q];
      if (s0 < bv[q]) { bv[q] = s0; bi[q] = j0; }
      if (s1 < bv[q]) { bv[q] = s1; bi[q] = j1; }
    }
  }
  __shared__ float rv[4][16];
  __shared__ int ri[4][16];
  const int lane = t & 63, w = t >> 6;
#pragma unroll
  for (int q = 0; q < 16; ++q) {
    float v = bv[q]; int ixq = bi[q];
    for (int off = 32; off; off >>= 1) {
      const float ov = __shfl_down(v, off);
      const int oi = __shfl_down(ixq, off);
      if (ov < v || (ov == v && oi < ixq)) { v = ov; ixq = oi; }
    }
    if (lane == 0) { rv[w][q] = v; ri[w][q] = ixq; }
  }
  __syncthreads();
  if (t < 16) {
    float v = rv[0][t]; int ixq = ri[0][t];
#pragma unroll
    for (int w2 = 1; w2 < 4; ++w2) {
      const float ov = rv[w2][t]; const int oi = ri[w2][t];
      if (ov < v || (ov == v && oi < ixq)) { v = ov; ixq = oi; }
    }
    out[q0 + t] = lab[ixq];
  }
}

extern "C" void kernel_launch(void* const* d_in, const int* in_sizes, int n_in,
                              void* d_out, int out_size, void* d_ws, size_t ws_size,
                              hipStream_t stream) {
  const float* x = (const float*)d_in[0];
  const float* y = (const float*)d_in[1];
  const float* lab = (const float*)d_in[2];
  float* out = (float*)d_out;

  const size_t o_ypk = 0;
  const size_t o_h  = o_ypk + (size_t)NM * ND * 4;  // 16 MB packed hi+lo
  const size_t o_p1 = o_h + (size_t)NM * 4;
  const size_t o_p2 = o_p1 + (size_t)NQ * NSLICE * 4;
  const size_t o_i1 = o_p2 + (size_t)NQ * NSLICE * 4;
  const size_t o_pk = o_i1 + (size_t)NQ * NSLICE * 4;
  const size_t o_wl = o_pk + (size_t)NQ * 8;
  const size_t o_md = o_wl + (size_t)WLCAP * 4;
  const size_t o_ct = o_md + (size_t)NQ * 4;
  const size_t need = o_ct + 16;

  if (ws_size >= need) {
    char* W = (char*)d_ws;
    unsigned short* ypk = (unsigned short*)(W + o_ypk);
    float* h = (float*)(W + o_h);
    float* pv1 = (float*)(W + o_p1);
    float* pv2 = (float*)(W + o_p2);
    int* pi1 = (int*)(W + o_i1);
    unsigned long long* packed = (unsigned long long*)(W + o_pk);
    int* wl = (int*)(W + o_wl);
    int* mode = (int*)(W + o_md);
    int* cnt = (int*)(W + o_ct);
    splity_kernel<<<NM / 2, BT, 0, stream>>>(y, ypk, cnt);
    hrow_kernel<<<NM / BT, BT, 0, stream>>>(y, h);
    nnA_mfma<<<(NQ / QB) * NSLICE, BT, 0, stream>>>(x, ypk, h, pv1, pi1, pv2);
    nnB_kernel<<<NQ / BT, BT, 0, stream>>>(x, y, h, lab, pv1, pi1, pv2,
                                           out, packed, mode, wl, cnt);
    nnC_kernel<<<256, BT, 0, stream>>>(x, y, h, wl, cnt, packed);
    nnD_kernel<<<NQ / BT, BT, 0, stream>>>(packed, mode, lab, out);
  } else if (ws_size >= (size_t)NM * 4) {
    float* h = (float*)d_ws;
    hrow_kernel<<<NM / BT, BT, 0, stream>>>(y, h);
    nn_fallback<1><<<NQ / 16, BT, 0, stream>>>(x, y, lab, h, out);
  } else {
    nn_fallback<0><<<NQ / 16, BT, 0, stream>>>(x, y, lab, nullptr, out);
  }
}

// Round 9
// 279.270 us; speedup vs baseline: 2.0706x; 1.0175x over previous
//
#include <hip/hip_runtime.h>

// 1-NN via 1-term bf16 MFMA screen + provable per-query Cauchy-Schwarz radius
// + exact fp32 rescore.  argmin_j ||x-y_j||^2 == argmin_j (0.5||y_j||^2 - x.y_j).
// Pass A (MFMA): d~ = h_j - xhi.yhi, per-(q,slice) top-2 min.
//   |d~ - D| = |xhi.ylo + xlo.y| <= (||x||+||xlo||)*maxYlo + ||xlo||*maxY  (HARD)
// Pass B: EPS_q = 2*bound*1.01 + 0.02; candidates = {d~ <= min + EPS_q};
//   single -> done; multi-slice singles -> exact serial dots; slice with >=2
//   candidates -> worklist slice rescan (pass C, exact, lex (d,j) atomicMin).
//
// Round 9: round 8 had MFMA 56% / LDS 46% / VALU 31% of the cycle budget --
// three pipes loaded by the 3-term split. 1-term screen cuts MFMA 3x, LDS 2x,
// staging 2x -> 32KB LDS/block -> NSLICE=16 -> 1024 blocks = 4/CU (2x TLP).
// Correctness stays deterministic: the radius is a hard bound on exact norms.

#define NQ 8192
#define NM 32768
#define ND 128
#define BT 256
#define NSLICE 16
#define SLICE (NM / NSLICE)   // 2048 rows -> 32 chunks of 64
#define QB 128                // queries per block (32 per wave)
#define WLCAP 16384

using bf16x8 = __attribute__((ext_vector_type(8))) short;
using f32x4  = __attribute__((ext_vector_type(4))) float;

__device__ __forceinline__ unsigned short bf16r(float f) {
  unsigned u = __float_as_uint(f);
  u += 0x7FFFu + ((u >> 16) & 1u);
  return (unsigned short)(u >> 16);
}
__device__ __forceinline__ float bf2f(unsigned short h) {
  return __uint_as_float(((unsigned)h) << 16);
}
__device__ __forceinline__ unsigned long long packsd(float s, int j) {
  unsigned u = __float_as_uint(s);
  u ^= (u & 0x80000000u) ? 0xFFFFFFFFu : 0x80000000u;  // monotone float->uint
  return (((unsigned long long)u) << 32) | (unsigned)j;
}
__device__ __forceinline__ void gload_lds16(const void* g, void* l) {
  __builtin_amdgcn_global_load_lds(
      (const __attribute__((address_space(1))) void*)g,
      (__attribute__((address_space(3))) void*)l, 16, 0, 0);
}

// ---- split y -> fragment-packed bf16 HI only: ypk[rg][ks][lane][8] ----
// rg = j>>4, ks = k-block of 32, lane = lg*16+(j&15), lg=(c>>3)&3, e=c&7.
__global__ void splity_kernel(const float* __restrict__ y,
                              unsigned short* __restrict__ ypk,
                              int* __restrict__ cnt) {
  if (blockIdx.x == 0 && threadIdx.x == 0) *cnt = 0;
  const int j = blockIdx.x * 2 + (threadIdx.x >> 7);
  const int c = threadIdx.x & 127;
  const float f = y[(size_t)j * ND + c];
  const int rg = j >> 4, jl = j & 15;
  const int ks = c >> 5, lg = (c >> 3) & 3, e = c & 7;
  const int lane = lg * 16 + jl;
  ypk[(size_t)rg * 2048 + ks * 512 + lane * 8 + e] = bf16r(f);
}

// ---- h[j]=0.5||y_j||^2 exact; also global maxes of ||y||^2 and ||ylo||^2 ----
__global__ void hrow_kernel(const float* __restrict__ y, float* __restrict__ h,
                            unsigned* __restrict__ scal) {
  const int j = blockIdx.x * blockDim.x + threadIdx.x;
  if (j >= NM) return;
  const float4* __restrict__ yp = (const float4*)(y + (size_t)j * ND);
  float s = 0.f, slo = 0.f;
#pragma unroll
  for (int u = 0; u < ND / 4; ++u) {
    const float4 v = yp[u];
    const float vv[4] = {v.x, v.y, v.z, v.w};
#pragma unroll
    for (int e = 0; e < 4; ++e) {
      s = fmaf(vv[e], vv[e], s);
      const float lo = vv[e] - bf2f(bf16r(vv[e]));
      slo = fmaf(lo, lo, slo);
    }
  }
  h[j] = 0.5f * s;
  // wave-reduce maxes, one atomic per wave (values >= 0: uint order == float order)
  float ms = s, mslo = slo;
  for (int off = 32; off; off >>= 1) {
    ms = fmaxf(ms, __shfl_xor(ms, off));
    mslo = fmaxf(mslo, __shfl_xor(mslo, off));
  }
  if ((threadIdx.x & 63) == 0) {
    atomicMax(&scal[0], __float_as_uint(ms));
    atomicMax(&scal[1], __float_as_uint(mslo));
  }
}

// ---- per-query ||x||^2 and ||xlo||^2 ----
__global__ void xnorm_kernel(const float* __restrict__ x, float* __restrict__ x2,
                             float* __restrict__ xlo2) {
  const int q = blockIdx.x * blockDim.x + threadIdx.x;
  if (q >= NQ) return;
  const float4* __restrict__ xp = (const float4*)(x + (size_t)q * ND);
  float s = 0.f, slo = 0.f;
#pragma unroll
  for (int u = 0; u < ND / 4; ++u) {
    const float4 v = xp[u];
    const float vv[4] = {v.x, v.y, v.z, v.w};
#pragma unroll
    for (int e = 0; e < 4; ++e) {
      s = fmaf(vv[e], vv[e], s);
      const float lo = vv[e] - bf2f(bf16r(vv[e]));
      slo = fmaf(lo, lo, slo);
    }
  }
  x2[q] = s;
  xlo2[q] = slo;
}

// ---- pass A: 1-term MFMA screen, shared LDS chunk, per-(q,slice) top-2 ----
// LDS chunk (shorts): [rg(4)][ks(4)][lane(64)][8] = 8192 shorts = 16KB.
#define LDFR(FH, ST) do {                                                      \
    _Pragma("unroll")                                                          \
    for (int ks = 0; ks < 4; ++ks)                                             \
      FH[ks] = *(const bf16x8*)&bufc[(ST) * 2048 + ks * 512 + lane * 8];       \
  } while (0)

#define MFST(FH, ST) do {                                                      \
    f32x4 a0 = {0.f, 0.f, 0.f, 0.f}, a1 = {0.f, 0.f, 0.f, 0.f};               \
    __builtin_amdgcn_s_setprio(1);                                             \
    _Pragma("unroll")                                                          \
    for (int ks = 0; ks < 4; ++ks) {                                           \
      a0 = __builtin_amdgcn_mfma_f32_16x16x32_bf16(xh_[0][ks], FH[ks], a0, 0, 0, 0); \
      a1 = __builtin_amdgcn_mfma_f32_16x16x32_bf16(xh_[1][ks], FH[ks], a1, 0, 0, 0); \
    }                                                                          \
    __builtin_amdgcn_s_setprio(0);                                             \
    const int jj_ = jb + (ST) * 16 + l15;                                      \
    const float hv_ = hv[ST];                                                  \
    _Pragma("unroll")                                                          \
    for (int p = 0; p < 8; ++p) {                                              \
      const float s_ = hv_ - ((p < 4) ? a0[p] : a1[p - 4]);                    \
      const bool lt_ = s_ < v1[p];                                             \
      v2[p] = __builtin_amdgcn_fmed3f(v1[p], v2[p], s_);                       \
      v1[p] = fminf(v1[p], s_);                                                \
      ix[p] = lt_ ? jj_ : ix[p];                                               \
    }                                                                          \
  } while (0)

__global__ __launch_bounds__(BT, 4) void nnA_mfma(
    const float* __restrict__ x, const unsigned short* __restrict__ ypk,
    const float* __restrict__ h,
    float* __restrict__ pv1, int* __restrict__ pi1, float* __restrict__ pv2) {
  __shared__ unsigned short yl2[2][8192];  // double-buffered 64-row chunk (2x16KB)
  const int t = threadIdx.x, lane = t & 63, w = t >> 6;
  const int l15 = lane & 15, lg = lane >> 4;
  const int slice = blockIdx.x & (NSLICE - 1);
  const int q0 = (blockIdx.x >> 4) * QB + w * 32;  // this wave's 32 queries

  // x hi fragments; A-frag: row=l15 (query), k = ks*32 + lg*8 + i
  bf16x8 xh_[2][4];
#pragma unroll
  for (int qt = 0; qt < 2; ++qt)
#pragma unroll
    for (int ks = 0; ks < 4; ++ks) {
      const float* xp = x + (size_t)(q0 + qt * 16 + l15) * ND + ks * 32 + lg * 8;
      const float4 f0 = *(const float4*)xp;
      const float4 f1 = *(const float4*)(xp + 4);
      const float ff[8] = {f0.x, f0.y, f0.z, f0.w, f1.x, f1.y, f1.z, f1.w};
      bf16x8 vh;
#pragma unroll
      for (int i = 0; i < 8; ++i) vh[i] = (short)bf16r(ff[i]);
      xh_[qt][ks] = vh;
    }

  float v1[8], v2[8]; int ix[8];
#pragma unroll
  for (int p = 0; p < 8; ++p) { v1[p] = 3.4e38f; v2[p] = 3.4e38f; ix[p] = 0; }

  // Slice base in ypk (shorts): chunk = 8192 shorts (64 rows).
  const size_t sbase = (size_t)slice * (SLICE / 16) * 2048;

  // Prologue: stage chunk 0 into buf 0; wave w stages row-group w (4 x 1KB).
  {
    const unsigned short* src = ypk + sbase + w * 2048 + lane * 8;
#pragma unroll
    for (int s = 0; s < 4; ++s)
      gload_lds16(src + s * 512, &yl2[0][w * 2048 + s * 512]);
  }
  __syncthreads();

#pragma unroll 1
  for (int it = 0; it < SLICE / 64; ++it) {
    const int cur = it & 1;
    if (it < SLICE / 64 - 1) {
      const unsigned short* src =
          ypk + sbase + (size_t)(it + 1) * 8192 + w * 2048 + lane * 8;
      unsigned short* dst = &yl2[cur ^ 1][w * 2048];
#pragma unroll
      for (int s = 0; s < 4; ++s)
        gload_lds16(src + s * 512, dst + s * 512);
    }
    const int jb = slice * SLICE + it * 64;
    float hv[4];
#pragma unroll
    for (int st = 0; st < 4; ++st) hv[st] = h[jb + st * 16 + l15];

    const unsigned short* __restrict__ bufc = &yl2[cur][0];
    bf16x8 FA[4], FB[4];
    LDFR(FA, 0);
    LDFR(FB, 1);
    MFST(FA, 0);
    LDFR(FA, 2);
    MFST(FB, 1);
    LDFR(FB, 3);
    MFST(FA, 2);
    MFST(FB, 3);
    __syncthreads();
  }

  // Reduce across the 16 lanes sharing each query; waves own disjoint queries.
#pragma unroll
  for (int p = 0; p < 8; ++p) {
    float m1 = v1[p], m2 = v2[p]; int i1 = ix[p];
    for (int off = 1; off < 16; off <<= 1) {
      const float o1 = __shfl_xor(m1, off);
      const float o2 = __shfl_xor(m2, off);
      const int oi = __shfl_xor(i1, off);
      const float n2 = fminf(fmaxf(m1, o1), fminf(m2, o2));
      if (o1 < m1 || (o1 == m1 && oi < i1)) { m1 = o1; i1 = oi; }
      m2 = n2;
    }
    if (l15 == 0) {
      const int q = q0 + (p >> 2) * 16 + lg * 4 + (p & 3);  // D-layout row
      pv1[(size_t)q * NSLICE + slice] = m1;
      pv2[(size_t)q * NSLICE + slice] = m2;
      pi1[(size_t)q * NSLICE + slice] = i1;
    }
  }
}

// exact fp32 key; k-ascending chain (identical in B and C)
__device__ __forceinline__ unsigned long long exact_key(
    const float* __restrict__ x, const float* __restrict__ y,
    const float* __restrict__ h, int q, int j) {
  const float* xp = x + (size_t)q * ND;
  const float* yp = y + (size_t)j * ND;
  float dot = 0.f;
#pragma unroll
  for (int k = 0; k < ND; ++k) dot = fmaf(xp[k], yp[k], dot);
  return packsd(h[j] - dot, j);
}

// ---- pass B: candidate logic with per-query hard radius ----
__global__ void nnB_kernel(const float* __restrict__ x, const float* __restrict__ y,
                           const float* __restrict__ h, const float* __restrict__ lab,
                           const float* __restrict__ pv1, const int* __restrict__ pi1,
                           const float* __restrict__ pv2,
                           const float* __restrict__ x2, const float* __restrict__ xlo2,
                           const unsigned* __restrict__ scal,
                           float* __restrict__ out,
                           unsigned long long* __restrict__ packed,
                           int* __restrict__ mode, int* __restrict__ wl,
                           int* __restrict__ cnt) {
  const int q = blockIdx.x * blockDim.x + threadIdx.x;
  if (q >= NQ) return;
  const float maxY = sqrtf(__uint_as_float(scal[0]));
  const float maxYlo = sqrtf(__uint_as_float(scal[1]));
  const float ex = sqrtf(x2[q]), exl = sqrtf(xlo2[q]);
  // |d~ - D| <= (||x||+||xlo||)*maxYlo + ||xlo||*maxY  (Cauchy-Schwarz, exact norms)
  const float epsq = 2.0f * ((ex + exl) * maxYlo + exl * maxY) * 1.01f + 0.02f;
  float m = 3.4e38f;
  for (int s = 0; s < NSLICE; ++s) m = fminf(m, pv1[q * NSLICE + s]);
  const float thr = m + epsq;
  int singles[NSLICE], resc[NSLICE], ns = 0, nr = 0;
  for (int s = 0; s < NSLICE; ++s) {
    if (pv1[q * NSLICE + s] <= thr) {
      if (pv2[q * NSLICE + s] <= thr) resc[nr++] = s;
      else singles[ns++] = pi1[q * NSLICE + s];
    }
  }
  if (nr == 0) {
    if (ns == 1) { out[q] = lab[singles[0]]; mode[q] = 0; return; }
    unsigned long long b = ~0ull;
    for (int i = 0; i < ns; ++i) {
      const unsigned long long k = exact_key(x, y, h, q, singles[i]);
      b = k < b ? k : b;
    }
    out[q] = lab[(unsigned)(b & 0xFFFFFFFFull)];
    mode[q] = 0; return;
  }
  const int base = atomicAdd(cnt, nr);
  for (int i = 0; i < nr; ++i)
    if (base + i < WLCAP) wl[base + i] = (q << 4) | resc[i];
  unsigned long long b = ~0ull;
  for (int i = 0; i < ns; ++i) {
    const unsigned long long k = exact_key(x, y, h, q, singles[i]);
    b = k < b ? k : b;
  }
  if (base + nr <= WLCAP) {
    packed[q] = b; mode[q] = 1;  // pass C fills the rest
  } else {  // overflow (practically impossible): resolve fully serial
    for (int i = 0; i < nr; ++i) {
      const int j0 = resc[i] * SLICE;
      for (int j = j0; j < j0 + SLICE; ++j) {
        const unsigned long long k = exact_key(x, y, h, q, j);
        b = k < b ? k : b;
      }
    }
    out[q] = lab[(unsigned)(b & 0xFFFFFFFFull)]; mode[q] = 0;
  }
}

// ---- pass C: rescan worklist slices, exact fp32, atomicMin ----
__global__ __launch_bounds__(BT) void nnC_kernel(
    const float* __restrict__ x, const float* __restrict__ y,
    const float* __restrict__ h, const int* __restrict__ wl,
    const int* __restrict__ cnt, unsigned long long* __restrict__ packed) {
  __shared__ float xs[ND];
  __shared__ unsigned long long wb[4];
  int n = *cnt; if (n > WLCAP) n = WLCAP;
  const int t = threadIdx.x, lane = t & 63, w = t >> 6;
  for (int e = blockIdx.x; e < n; e += gridDim.x) {
    const int v = wl[e], q = v >> 4, sl = v & 15;
    __syncthreads();
    if (t < ND) xs[t] = x[(size_t)q * ND + t];
    __syncthreads();
    unsigned long long best = ~0ull;
    for (int i = 0; i < SLICE / BT; ++i) {
      const int j = sl * SLICE + i * BT + t;
      const float* yp = y + (size_t)j * ND;
      float dot = 0.f;
#pragma unroll
      for (int k = 0; k < ND; ++k) dot = fmaf(xs[k], yp[k], dot);
      const unsigned long long kk = packsd(h[j] - dot, j);
      if (kk < best) best = kk;
    }
    for (int off = 32; off; off >>= 1) {
      const unsigned long long o = __shfl_xor(best, off);
      if (o < best) best = o;
    }
    if (lane == 0) wb[w] = best;
    __syncthreads();
    if (t == 0) {
      unsigned long long b = wb[0];
      for (int w2 = 1; w2 < 4; ++w2) if (wb[w2] < b) b = wb[w2];
      atomicMin(packed + q, b);
    }
  }
}

// ---- pass D: finalize pending queries ----
__global__ void nnD_kernel(const unsigned long long* __restrict__ packed,
                           const int* __restrict__ mode,
                           const float* __restrict__ lab, float* __restrict__ out) {
  const int q = blockIdx.x * blockDim.x + threadIdx.x;
  if (q >= NQ) return;
  if (mode[q]) out[q] = lab[(unsigned)(packed[q] & 0xFFFFFFFFull)];
}

// ---- fallback (round-2 kernel, known-passing) ----
__global__ void hrow_fb(const float* __restrict__ y, float* __restrict__ h) {
  const int j = blockIdx.x * blockDim.x + threadIdx.x;
  if (j >= NM) return;
  const float4* __restrict__ yp = (const float4*)(y + (size_t)j * ND);
  float s = 0.f;
#pragma unroll
  for (int u = 0; u < ND / 4; ++u) {
    const float4 v = yp[u];
    s = fmaf(v.x, v.x, s); s = fmaf(v.y, v.y, s);
    s = fmaf(v.z, v.z, s); s = fmaf(v.w, v.w, s);
  }
  h[j] = 0.5f * s;
}

template <int USE_H>
__global__ __launch_bounds__(BT, 2) void nn_fallback(
    const float* __restrict__ x, const float* __restrict__ y,
    const float* __restrict__ lab, const float* __restrict__ h,
    float* __restrict__ out) {
  const int t = threadIdx.x;
  const int q0 = blockIdx.x * 16;
  float bv[16]; int bi[16];
#pragma unroll
  for (int q = 0; q < 16; ++q) { bv[q] = 3.4e38f; bi[q] = 0; }
  for (int it = 0; it < NM / 512; ++it) {
    const int j0 = it * 512 + t, j1 = j0 + 256;
    const float4* __restrict__ yp0 = (const float4*)(y + (size_t)j0 * ND);
    const float4* __restrict__ yp1 = (const float4*)(y + (size_t)j1 * ND);
    float acc0[16], acc1[16];
#pragma unroll
    for (int q = 0; q < 16; ++q) { acc0[q] = 0.f; acc1[q] = 0.f; }
    float y20 = 0.f, y21 = 0.f;
#pragma unroll 1
    for (int kc = 0; kc < 4; ++kc) {
      float4 a0[8], a1[8];
#pragma unroll
      for (int u = 0; u < 8; ++u) { a0[u] = yp0[kc * 8 + u]; a1[u] = yp1[kc * 8 + u]; }
      if (USE_H == 0) {
#pragma unroll
        for (int u = 0; u < 8; ++u) {
          y20 = fmaf(a0[u].x, a0[u].x, y20); y20 = fmaf(a0[u].y, a0[u].y, y20);
          y20 = fmaf(a0[u].z, a0[u].z, y20); y20 = fmaf(a0[u].w, a0[u].w, y20);
          y21 = fmaf(a1[u].x, a1[u].x, y21); y21 = fmaf(a1[u].y, a1[u].y, y21);
          y21 = fmaf(a1[u].z, a1[u].z, y21); y21 = fmaf(a1[u].w, a1[u].w, y21);
        }
      }
#pragma unroll
      for (int q = 0; q < 16; ++q) {
        const float* __restrict__ xq = x + (size_t)(q0 + q) * ND + kc * 32;
        float s0 = acc0[q], s1 = acc1[q];
#pragma unroll
        for (int u = 0; u < 8; ++u) {
          const float4 xv = *(const float4*)(xq + u * 4);
          s0 = fmaf(a0[u].x, xv.x, s0); s0 = fmaf(a0[u].y, xv.y, s0);
          s0 = fmaf(a0[u].z, xv.z, s0); s0 = fmaf(a0[u].w, xv.w, s0);
          s1 = fmaf(a1[u].x, xv.x, s1); s1 = fmaf(a1[u].y, xv.y, s1);
          s1 = fmaf(a1[u].z, xv.z, s1); s1 = fmaf(a1[u].w, xv.w, s1);
        }
        acc0[q] = s0; acc1[q] = s1;
      }
    }
    float h0, h1;
    if (USE_H) { h0 = h[j0]; h1 = h[j1]; }
    else { h0 = 0.5f * y20; h1 = 0.5f * y21; }
#pragma unroll
    for (int q = 0; q < 16; ++q) {
      const float s0 = h0 - acc0[q], s1 = h1 - acc1[q];
      if (s0 < bv[q]) { bv[q] = s0; bi[q] = j0; }
      if (s1 < bv[q]) { bv[q] = s1; bi[q] = j1; }
    }
  }
  __shared__ float rv[4][16];
  __shared__ int ri[4][16];
  const int lane = t & 63, w = t >> 6;
#pragma unroll
  for (int q = 0; q < 16; ++q) {
    float v = bv[q]; int ixq = bi[q];
    for (int off = 32; off; off >>= 1) {
      const float ov = __shfl_down(v, off);
      const int oi = __shfl_down(ixq, off);
      if (ov < v || (ov == v && oi < ixq)) { v = ov; ixq = oi; }
    }
    if (lane == 0) { rv[w][q] = v; ri[w][q] = ixq; }
  }
  __syncthreads();
  if (t < 16) {
    float v = rv[0][t]; int ixq = ri[0][t];
#pragma unroll
    for (int w2 = 1; w2 < 4; ++w2) {
      const float ov = rv[w2][t]; const int oi = ri[w2][t];
      if (ov < v || (ov == v && oi < ixq)) { v = ov; ixq = oi; }
    }
    out[q0 + t] = lab[ixq];
  }
}

extern "C" void kernel_launch(void* const* d_in, const int* in_sizes, int n_in,
                              void* d_out, int out_size, void* d_ws, size_t ws_size,
                              hipStream_t stream) {
  const float* x = (const float*)d_in[0];
  const float* y = (const float*)d_in[1];
  const float* lab = (const float*)d_in[2];
  float* out = (float*)d_out;

  const size_t o_ypk = 0;                                // 8 MB hi-only packed
  const size_t o_h   = o_ypk + (size_t)NM * ND * 2;
  const size_t o_x2  = o_h + (size_t)NM * 4;
  const size_t o_xl2 = o_x2 + (size_t)NQ * 4;
  const size_t o_sc  = o_xl2 + (size_t)NQ * 4;
  const size_t o_p1  = o_sc + 16;
  const size_t o_p2  = o_p1 + (size_t)NQ * NSLICE * 4;
  const size_t o_i1  = o_p2 + (size_t)NQ * NSLICE * 4;
  const size_t o_pk  = o_i1 + (size_t)NQ * NSLICE * 4;
  const size_t o_wl  = o_pk + (size_t)NQ * 8;
  const size_t o_md  = o_wl + (size_t)WLCAP * 4;
  const size_t o_ct  = o_md + (size_t)NQ * 4;
  const size_t need  = o_ct + 16;

  if (ws_size >= need) {
    char* W = (char*)d_ws;
    unsigned short* ypk = (unsigned short*)(W + o_ypk);
    float* h = (float*)(W + o_h);
    float* x2 = (float*)(W + o_x2);
    float* xlo2 = (float*)(W + o_xl2);
    unsigned* scal = (unsigned*)(W + o_sc);
    float* pv1 = (float*)(W + o_p1);
    float* pv2 = (float*)(W + o_p2);
    int* pi1 = (int*)(W + o_i1);
    unsigned long long* packed = (unsigned long long*)(W + o_pk);
    int* wl = (int*)(W + o_wl);
    int* mode = (int*)(W + o_md);
    int* cnt = (int*)(W + o_ct);
    hipMemsetAsync(scal, 0, 16, stream);
    splity_kernel<<<NM / 2, BT, 0, stream>>>(y, ypk, cnt);
    hrow_kernel<<<NM / BT, BT, 0, stream>>>(y, h, scal);
    xnorm_kernel<<<NQ / BT, BT, 0, stream>>>(x, x2, xlo2);
    nnA_mfma<<<(NQ / QB) * NSLICE, BT, 0, stream>>>(x, ypk, h, pv1, pi1, pv2);
    nnB_kernel<<<NQ / BT, BT, 0, stream>>>(x, y, h, lab, pv1, pi1, pv2,
                                           x2, xlo2, scal, out, packed, mode, wl, cnt);
    nnC_kernel<<<256, BT, 0, stream>>>(x, y, h, wl, cnt, packed);
    nnD_kernel<<<NQ / BT, BT, 0, stream>>>(packed, mode, lab, out);
  } else if (ws_size >= (size_t)NM * 4) {
    float* h = (float*)d_ws;
    hrow_fb<<<NM / BT, BT, 0, stream>>>(y, h);
    nn_fallback<1><<<NQ / 16, BT, 0, stream>>>(x, y, lab, h, out);
  } else {
    nn_fallback<0><<<NQ / 16, BT, 0, stream>>>(x, y, lab, nullptr, out);
  }
}

// Round 10
// 273.292 us; speedup vs baseline: 2.1158x; 1.0219x over previous
//
#include <hip/hip_runtime.h>

// 1-NN via 1-term bf16 MFMA screen + provable per-query Cauchy-Schwarz radius
// + exact fp32 rescore.  argmin_j ||x-y_j||^2 == argmin_j (0.5||y_j||^2 - x.y_j).
// Pass A (MFMA): d~ = h_j - xhi.yhi, per-(q,slice) top-2 min.
//   |d~ - D| = |xhi.ylo + xlo.y| <= (||x||+||xlo||)*maxYlo + ||xlo||*maxY  (HARD)
// Pass B: EPS_q = 2*bound*1.01 + 0.02; candidates = {d~ <= min + EPS_q};
//   single -> done; multi-slice singles -> exact serial dots; slice with >=2
//   candidates -> worklist slice rescan (pass C, exact, lex (d,j) atomicMin).
//
// Round 10: (a) nnA QW=64 queries/wave (4 A-tiles, BT=128): LDS-read demand and
// staging traffic halve per MFMA, barriers halve; (b) merged prep kernel (split+
// pack + h + scal maxes + x norms) removes a 16MB y re-read and 2 launches.
// Rescore logic byte-identical to round 9 (passed, absmax 0.0).

#define NQ 8192
#define NM 32768
#define ND 128
#define BT 128                // nnA block: 2 waves
#define NSLICE 16
#define SLICE (NM / NSLICE)   // 2048 rows -> 32 chunks of 64
#define QW 64                 // queries per wave
#define QB (QW * 2)           // 128 queries per block
#define WLCAP 16384
#define PREP_YB 512           // prep blocks for y (64 rows each)
#define PREP_XB 128           // prep blocks for x (64 rows each)

using bf16x8 = __attribute__((ext_vector_type(8))) short;
using f32x4  = __attribute__((ext_vector_type(4))) float;

__device__ __forceinline__ unsigned short bf16r(float f) {
  unsigned u = __float_as_uint(f);
  u += 0x7FFFu + ((u >> 16) & 1u);
  return (unsigned short)(u >> 16);
}
__device__ __forceinline__ float bf2f(unsigned short h) {
  return __uint_as_float(((unsigned)h) << 16);
}
__device__ __forceinline__ unsigned long long packsd(float s, int j) {
  unsigned u = __float_as_uint(s);
  u ^= (u & 0x80000000u) ? 0xFFFFFFFFu : 0x80000000u;  // monotone float->uint
  return (((unsigned long long)u) << 32) | (unsigned)j;
}
__device__ __forceinline__ void gload_lds16(const void* g, void* l) {
  __builtin_amdgcn_global_load_lds(
      (const __attribute__((address_space(1))) void*)g,
      (__attribute__((address_space(3))) void*)l, 16, 0, 0);
}

// ---- merged prep: y -> packed bf16 hi (ypk[rg][ks][lane][8]) + h + scal maxes;
//      x -> per-query ||x||^2, ||xlo||^2.  One wave per row, 16 rows per wave.
__global__ __launch_bounds__(256) void prep_kernel(
    const float* __restrict__ y, const float* __restrict__ x,
    unsigned short* __restrict__ ypk, float* __restrict__ h,
    float* __restrict__ x2, float* __restrict__ xlo2,
    unsigned* __restrict__ scal, int* __restrict__ cnt) {
  const int wv = threadIdx.x >> 6, l = threadIdx.x & 63;
  if (blockIdx.x == 0 && threadIdx.x == 0) *cnt = 0;
  if (blockIdx.x < PREP_YB) {
    __shared__ float bm[4][2];
    float ms = 0.f, mslo = 0.f;
    const int j00 = blockIdx.x * 64 + wv * 16;
#pragma unroll
    for (int r = 0; r < 16; ++r) {
      const int j = j00 + r;
      const float2 v = *(const float2*)(y + (size_t)j * ND + l * 2);
      const unsigned short hb0 = bf16r(v.x), hb1 = bf16r(v.y);
      const float lo0 = v.x - bf2f(hb0), lo1 = v.y - bf2f(hb1);
      const int c0 = l * 2;  // c0&7 even -> the two shorts share one aligned uint
      const int idx = ((j >> 4) * 2048) + ((c0 >> 5) * 512) +
                      ((((c0 >> 3) & 3) * 16 + (j & 15)) * 8) + (c0 & 7);
      *(unsigned*)&ypk[idx] = (unsigned)hb0 | ((unsigned)hb1 << 16);
      float s = fmaf(v.y, v.y, v.x * v.x);
      float slo = fmaf(lo1, lo1, lo0 * lo0);
      for (int off = 32; off; off >>= 1) {
        s += __shfl_xor(s, off);
        slo += __shfl_xor(slo, off);
      }
      if (l == 0) h[j] = 0.5f * s;
      ms = fmaxf(ms, s);
      mslo = fmaxf(mslo, slo);
    }
    if (l == 0) { bm[wv][0] = ms; bm[wv][1] = mslo; }
    __syncthreads();
    if (threadIdx.x == 0) {
      float a = bm[0][0], b = bm[0][1];
#pragma unroll
      for (int w2 = 1; w2 < 4; ++w2) { a = fmaxf(a, bm[w2][0]); b = fmaxf(b, bm[w2][1]); }
      atomicMax(&scal[0], __float_as_uint(a));
      atomicMax(&scal[1], __float_as_uint(b));
    }
  } else {
    const int q00 = (blockIdx.x - PREP_YB) * 64 + wv * 16;
#pragma unroll
    for (int r = 0; r < 16; ++r) {
      const int q = q00 + r;
      const float2 v = *(const float2*)(x + (size_t)q * ND + l * 2);
      const unsigned short hb0 = bf16r(v.x), hb1 = bf16r(v.y);
      const float lo0 = v.x - bf2f(hb0), lo1 = v.y - bf2f(hb1);
      float s = fmaf(v.y, v.y, v.x * v.x);
      float slo = fmaf(lo1, lo1, lo0 * lo0);
      for (int off = 32; off; off >>= 1) {
        s += __shfl_xor(s, off);
        slo += __shfl_xor(slo, off);
      }
      if (l == 0) { x2[q] = s; xlo2[q] = slo; }
    }
  }
}

// ---- pass A: 1-term MFMA screen, QW=64/wave, shared LDS chunk, top-2/(q,slice) ----
// LDS chunk (shorts): [rg(4)][ks(4)][lane(64)][8] = 8192 shorts = 16KB.
#define LDFR(FH, ST) do {                                                      \
    _Pragma("unroll")                                                          \
    for (int ks = 0; ks < 4; ++ks)                                             \
      FH[ks] = *(const bf16x8*)&bufc[(ST) * 2048 + ks * 512 + lane * 8];       \
  } while (0)

#define MFST(FH, ST) do {                                                      \
    f32x4 a0 = {0.f, 0.f, 0.f, 0.f}, a1 = {0.f, 0.f, 0.f, 0.f};               \
    f32x4 a2 = {0.f, 0.f, 0.f, 0.f}, a3 = {0.f, 0.f, 0.f, 0.f};               \
    __builtin_amdgcn_s_setprio(1);                                             \
    _Pragma("unroll")                                                          \
    for (int ks = 0; ks < 4; ++ks) {                                           \
      a0 = __builtin_amdgcn_mfma_f32_16x16x32_bf16(xh_[0][ks], FH[ks], a0, 0, 0, 0); \
      a1 = __builtin_amdgcn_mfma_f32_16x16x32_bf16(xh_[1][ks], FH[ks], a1, 0, 0, 0); \
      a2 = __builtin_amdgcn_mfma_f32_16x16x32_bf16(xh_[2][ks], FH[ks], a2, 0, 0, 0); \
      a3 = __builtin_amdgcn_mfma_f32_16x16x32_bf16(xh_[3][ks], FH[ks], a3, 0, 0, 0); \
    }                                                                          \
    __builtin_amdgcn_s_setprio(0);                                             \
    const int jj_ = jb + (ST) * 16 + l15;                                      \
    const float hv_ = hv[ST];                                                  \
    _Pragma("unroll")                                                          \
    for (int p = 0; p < 16; ++p) {                                             \
      const float aa = (p < 4) ? a0[p & 3] : (p < 8) ? a1[p & 3]               \
                       : (p < 12) ? a2[p & 3] : a3[p & 3];                     \
      const float s_ = hv_ - aa;                                               \
      const bool lt_ = s_ < v1[p];                                             \
      v2[p] = __builtin_amdgcn_fmed3f(v1[p], v2[p], s_);                       \
      v1[p] = fminf(v1[p], s_);                                                \
      ix[p] = lt_ ? jj_ : ix[p];                                               \
    }                                                                          \
  } while (0)

__global__ __launch_bounds__(BT, 2) void nnA_mfma(
    const float* __restrict__ x, const unsigned short* __restrict__ ypk,
    const float* __restrict__ h,
    float* __restrict__ pv1, int* __restrict__ pi1, float* __restrict__ pv2) {
  __shared__ unsigned short yl2[2][8192];  // double-buffered 64-row chunk (2x16KB)
  const int t = threadIdx.x, lane = t & 63, w = t >> 6;
  const int l15 = lane & 15, lg = lane >> 4;
  const int slice = blockIdx.x & (NSLICE - 1);
  const int q0 = (blockIdx.x >> 4) * QB + w * QW;  // this wave's 64 queries

  // x hi fragments, 4 tiles; A-frag: row=l15 (query), k = ks*32 + lg*8 + i
  bf16x8 xh_[4][4];
#pragma unroll
  for (int qt = 0; qt < 4; ++qt)
#pragma unroll
    for (int ks = 0; ks < 4; ++ks) {
      const float* xp = x + (size_t)(q0 + qt * 16 + l15) * ND + ks * 32 + lg * 8;
      const float4 f0 = *(const float4*)xp;
      const float4 f1 = *(const float4*)(xp + 4);
      const float ff[8] = {f0.x, f0.y, f0.z, f0.w, f1.x, f1.y, f1.z, f1.w};
      bf16x8 vh;
#pragma unroll
      for (int i = 0; i < 8; ++i) vh[i] = (short)bf16r(ff[i]);
      xh_[qt][ks] = vh;
    }

  float v1[16], v2[16]; int ix[16];
#pragma unroll
  for (int p = 0; p < 16; ++p) { v1[p] = 3.4e38f; v2[p] = 3.4e38f; ix[p] = 0; }

  // Slice base in ypk (shorts): chunk = 8192 shorts (64 rows).
  const size_t sbase = (size_t)slice * (SLICE / 16) * 2048;

  // Prologue: stage chunk 0; wave w stages its half (8 x 1KB).
  {
    const unsigned short* src = ypk + sbase + w * 4096 + lane * 8;
#pragma unroll
    for (int s = 0; s < 8; ++s)
      gload_lds16(src + s * 512, &yl2[0][w * 4096 + s * 512]);
  }
  __syncthreads();

#pragma unroll 1
  for (int it = 0; it < SLICE / 64; ++it) {
    const int cur = it & 1;
    if (it < SLICE / 64 - 1) {
      const unsigned short* src =
          ypk + sbase + (size_t)(it + 1) * 8192 + w * 4096 + lane * 8;
      unsigned short* dst = &yl2[cur ^ 1][w * 4096];
#pragma unroll
      for (int s = 0; s < 8; ++s)
        gload_lds16(src + s * 512, dst + s * 512);
    }
    const int jb = slice * SLICE + it * 64;
    float hv[4];
#pragma unroll
    for (int st = 0; st < 4; ++st) hv[st] = h[jb + st * 16 + l15];

    const unsigned short* __restrict__ bufc = &yl2[cur][0];
    bf16x8 FA[4], FB[4];
    LDFR(FA, 0);
    LDFR(FB, 1);
    MFST(FA, 0);
    LDFR(FA, 2);
    MFST(FB, 1);
    LDFR(FB, 3);
    MFST(FA, 2);
    MFST(FB, 3);
    __syncthreads();
  }

  // Reduce across the 16 lanes sharing each query; waves own disjoint queries.
#pragma unroll
  for (int p = 0; p < 16; ++p) {
    float m1 = v1[p], m2 = v2[p]; int i1 = ix[p];
    for (int off = 1; off < 16; off <<= 1) {
      const float o1 = __shfl_xor(m1, off);
      const float o2 = __shfl_xor(m2, off);
      const int oi = __shfl_xor(i1, off);
      const float n2 = fminf(fmaxf(m1, o1), fminf(m2, o2));
      if (o1 < m1 || (o1 == m1 && oi < i1)) { m1 = o1; i1 = oi; }
      m2 = n2;
    }
    if (l15 == 0) {
      const int q = q0 + (p >> 2) * 16 + lg * 4 + (p & 3);  // D-layout row
      pv1[(size_t)q * NSLICE + slice] = m1;
      pv2[(size_t)q * NSLICE + slice] = m2;
      pi1[(size_t)q * NSLICE + slice] = i1;
    }
  }
}

// exact fp32 key; k-ascending chain (identical in B and C)
__device__ __forceinline__ unsigned long long exact_key(
    const float* __restrict__ x, const float* __restrict__ y,
    const float* __restrict__ h, int q, int j) {
  const float* xp = x + (size_t)q * ND;
  const float* yp = y + (size_t)j * ND;
  float dot = 0.f;
#pragma unroll
  for (int k = 0; k < ND; ++k) dot = fmaf(xp[k], yp[k], dot);
  return packsd(h[j] - dot, j);
}

// ---- pass B: candidate logic with per-query hard radius ----
__global__ void nnB_kernel(const float* __restrict__ x, const float* __restrict__ y,
                           const float* __restrict__ h, const float* __restrict__ lab,
                           const float* __restrict__ pv1, const int* __restrict__ pi1,
                           const float* __restrict__ pv2,
                           const float* __restrict__ x2, const float* __restrict__ xlo2,
                           const unsigned* __restrict__ scal,
                           float* __restrict__ out,
                           unsigned long long* __restrict__ packed,
                           int* __restrict__ mode, int* __restrict__ wl,
                           int* __restrict__ cnt) {
  const int q = blockIdx.x * blockDim.x + threadIdx.x;
  if (q >= NQ) return;
  const float maxY = sqrtf(__uint_as_float(scal[0]));
  const float maxYlo = sqrtf(__uint_as_float(scal[1]));
  const float ex = sqrtf(x2[q]), exl = sqrtf(xlo2[q]);
  // |d~ - D| <= (||x||+||xlo||)*maxYlo + ||xlo||*maxY  (Cauchy-Schwarz, exact norms)
  const float epsq = 2.0f * ((ex + exl) * maxYlo + exl * maxY) * 1.01f + 0.02f;
  float m = 3.4e38f;
  for (int s = 0; s < NSLICE; ++s) m = fminf(m, pv1[q * NSLICE + s]);
  const float thr = m + epsq;
  int singles[NSLICE], resc[NSLICE], ns = 0, nr = 0;
  for (int s = 0; s < NSLICE; ++s) {
    if (pv1[q * NSLICE + s] <= thr) {
      if (pv2[q * NSLICE + s] <= thr) resc[nr++] = s;
      else singles[ns++] = pi1[q * NSLICE + s];
    }
  }
  if (nr == 0) {
    if (ns == 1) { out[q] = lab[singles[0]]; mode[q] = 0; return; }
    unsigned long long b = ~0ull;
    for (int i = 0; i < ns; ++i) {
      const unsigned long long k = exact_key(x, y, h, q, singles[i]);
      b = k < b ? k : b;
    }
    out[q] = lab[(unsigned)(b & 0xFFFFFFFFull)];
    mode[q] = 0; return;
  }
  const int base = atomicAdd(cnt, nr);
  for (int i = 0; i < nr; ++i)
    if (base + i < WLCAP) wl[base + i] = (q << 4) | resc[i];
  unsigned long long b = ~0ull;
  for (int i = 0; i < ns; ++i) {
    const unsigned long long k = exact_key(x, y, h, q, singles[i]);
    b = k < b ? k : b;
  }
  if (base + nr <= WLCAP) {
    packed[q] = b; mode[q] = 1;  // pass C fills the rest
  } else {  // overflow (practically impossible): resolve fully serial
    for (int i = 0; i < nr; ++i) {
      const int j0 = resc[i] * SLICE;
      for (int j = j0; j < j0 + SLICE; ++j) {
        const unsigned long long k = exact_key(x, y, h, q, j);
        b = k < b ? k : b;
      }
    }
    out[q] = lab[(unsigned)(b & 0xFFFFFFFFull)]; mode[q] = 0;
  }
}

// ---- pass C: rescan worklist slices, exact fp32, atomicMin ----
__global__ __launch_bounds__(256) void nnC_kernel(
    const float* __restrict__ x, const float* __restrict__ y,
    const float* __restrict__ h, const int* __restrict__ wl,
    const int* __restrict__ cnt, unsigned long long* __restrict__ packed) {
  __shared__ float xs[ND];
  __shared__ unsigned long long wb[4];
  int n = *cnt; if (n > WLCAP) n = WLCAP;
  const int t = threadIdx.x, lane = t & 63, w = t >> 6;
  for (int e = blockIdx.x; e < n; e += gridDim.x) {
    const int v = wl[e], q = v >> 4, sl = v & 15;
    __syncthreads();
    if (t < ND) xs[t] = x[(size_t)q * ND + t];
    __syncthreads();
    unsigned long long best = ~0ull;
    for (int i = 0; i < SLICE / 256; ++i) {
      const int j = sl * SLICE + i * 256 + t;
      const float* yp = y + (size_t)j * ND;
      float dot = 0.f;
#pragma unroll
      for (int k = 0; k < ND; ++k) dot = fmaf(xs[k], yp[k], dot);
      const unsigned long long kk = packsd(h[j] - dot, j);
      if (kk < best) best = kk;
    }
    for (int off = 32; off; off >>= 1) {
      const unsigned long long o = __shfl_xor(best, off);
      if (o < best) best = o;
    }
    if (lane == 0) wb[w] = best;
    __syncthreads();
    if (t == 0) {
      unsigned long long b = wb[0];
      for (int w2 = 1; w2 < 4; ++w2) if (wb[w2] < b) b = wb[w2];
      atomicMin(packed + q, b);
    }
  }
}

// ---- pass D: finalize pending queries ----
__global__ void nnD_kernel(const unsigned long long* __restrict__ packed,
                           const int* __restrict__ mode,
                           const float* __restrict__ lab, float* __restrict__ out) {
  const int q = blockIdx.x * blockDim.x + threadIdx.x;
  if (q >= NQ) return;
  if (mode[q]) out[q] = lab[(unsigned)(packed[q] & 0xFFFFFFFFull)];
}

// ---- fallback (round-2 kernel, known-passing) ----
__global__ void hrow_fb(const float* __restrict__ y, float* __restrict__ h) {
  const int j = blockIdx.x * blockDim.x + threadIdx.x;
  if (j >= NM) return;
  const float4* __restrict__ yp = (const float4*)(y + (size_t)j * ND);
  float s = 0.f;
#pragma unroll
  for (int u = 0; u < ND / 4; ++u) {
    const float4 v = yp[u];
    s = fmaf(v.x, v.x, s); s = fmaf(v.y, v.y, s);
    s = fmaf(v.z, v.z, s); s = fmaf(v.w, v.w, s);
  }
  h[j] = 0.5f * s;
}

template <int USE_H>
__global__ __launch_bounds__(256, 2) void nn_fallback(
    const float* __restrict__ x, const float* __restrict__ y,
    const float* __restrict__ lab, const float* __restrict__ h,
    float* __restrict__ out) {
  const int t = threadIdx.x;
  const int q0 = blockIdx.x * 16;
  float bv[16]; int bi[16];
#pragma unroll
  for (int q = 0; q < 16; ++q) { bv[q] = 3.4e38f; bi[q] = 0; }
  for (int it = 0; it < NM / 512; ++it) {
    const int j0 = it * 512 + t, j1 = j0 + 256;
    const float4* __restrict__ yp0 = (const float4*)(y + (size_t)j0 * ND);
    const float4* __restrict__ yp1 = (const float4*)(y + (size_t)j1 * ND);
    float acc0[16], acc1[16];
#pragma unroll
    for (int q = 0; q < 16; ++q) { acc0[q] = 0.f; acc1[q] = 0.f; }
    float y20 = 0.f, y21 = 0.f;
#pragma unroll 1
    for (int kc = 0; kc < 4; ++kc) {
      float4 a0[8], a1[8];
#pragma unroll
      for (int u = 0; u < 8; ++u) { a0[u] = yp0[kc * 8 + u]; a1[u] = yp1[kc * 8 + u]; }
      if (USE_H == 0) {
#pragma unroll
        for (int u = 0; u < 8; ++u) {
          y20 = fmaf(a0[u].x, a0[u].x, y20); y20 = fmaf(a0[u].y, a0[u].y, y20);
          y20 = fmaf(a0[u].z, a0[u].z, y20); y20 = fmaf(a0[u].w, a0[u].w, y20);
          y21 = fmaf(a1[u].x, a1[u].x, y21); y21 = fmaf(a1[u].y, a1[u].y, y21);
          y21 = fmaf(a1[u].z, a1[u].z, y21); y21 = fmaf(a1[u].w, a1[u].w, y21);
        }
      }
#pragma unroll
      for (int q = 0; q < 16; ++q) {
        const float* __restrict__ xq = x + (size_t)(q0 + q) * ND + kc * 32;
        float s0 = acc0[q], s1 = acc1[q];
#pragma unroll
        for (int u = 0; u < 8; ++u) {
          const float4 xv = *(const float4*)(xq + u * 4);
          s0 = fmaf(a0[u].x, xv.x, s0); s0 = fmaf(a0[u].y, xv.y, s0);
          s0 = fmaf(a0[u].z, xv.z, s0); s0 = fmaf(a0[u].w, xv.w, s0);
          s1 = fmaf(a1[u].x, xv.x, s1); s1 = fmaf(a1[u].y, xv.y, s1);
          s1 = fmaf(a1[u].z, xv.z, s1); s1 = fmaf(a1[u].w, xv.w, s1);
        }
        acc0[q] = s0; acc1[q] = s1;
      }
    }
    float h0, h1;
    if (USE_H) { h0 = h[j0]; h1 = h[j1]; }
    else { h0 = 0.5f * y20; h1 = 0.5f * y21; }
#pragma unroll
    for (int q = 0; q < 16; ++q) {
      const float s0 = h0 - acc0[q], s1 = h1 - acc1[q];
      if (s0 < bv[q]) { bv[q] = s0; bi[q] = j0; }
      if (s1 < bv[q]) { bv[q] = s1; bi[q] = j1; }
    }
  }
  __shared__ float rv[4][16];
  __shared__ int ri[4][16];
  const int lane = t & 63, w = t >> 6;
#pragma unroll
  for (int q = 0; q < 16; ++q) {
    float v = bv[q]; int ixq = bi[q];
    for (int off = 32; off; off >>= 1) {
      const float ov = __shfl_down(v, off);
      const int oi = __shfl_down(ixq, off);
      if (ov < v || (ov == v && oi < ixq)) { v = ov; ixq = oi; }
    }
    if (lane == 0) { rv[w][q] = v; ri[w][q] = ixq; }
  }
  __syncthreads();
  if (t < 16) {
    float v = rv[0][t]; int ixq = ri[0][t];
#pragma unroll
    for (int w2 = 1; w2 < 4; ++w2) {
      const float ov = rv[w2][t]; const int oi = ri[w2][t];
      if (ov < v || (ov == v && oi < ixq)) { v = ov; ixq = oi; }
    }
    out[q0 + t] = lab[ixq];
  }
}

extern "C" void kernel_launch(void* const* d_in, const int* in_sizes, int n_in,
                              void* d_out, int out_size, void* d_ws, size_t ws_size,
                              hipStream_t stream) {
  const float* x = (const float*)d_in[0];
  const float* y = (const float*)d_in[1];
  const float* lab = (const float*)d_in[2];
  float* out = (float*)d_out;

  const size_t o_ypk = 0;                                // 8 MB hi-only packed
  const size_t o_h   = o_ypk + (size_t)NM * ND * 2;
  const size_t o_x2  = o_h + (size_t)NM * 4;
  const size_t o_xl2 = o_x2 + (size_t)NQ * 4;
  const size_t o_sc  = o_xl2 + (size_t)NQ * 4;
  const size_t o_p1  = o_sc + 16;
  const size_t o_p2  = o_p1 + (size_t)NQ * NSLICE * 4;
  const size_t o_i1  = o_p2 + (size_t)NQ * NSLICE * 4;
  const size_t o_pk  = o_i1 + (size_t)NQ * NSLICE * 4;
  const size_t o_wl  = o_pk + (size_t)NQ * 8;
  const size_t o_md  = o_wl + (size_t)WLCAP * 4;
  const size_t o_ct  = o_md + (size_t)NQ * 4;
  const size_t need  = o_ct + 16;

  if (ws_size >= need) {
    char* W = (char*)d_ws;
    unsigned short* ypk = (unsigned short*)(W + o_ypk);
    float* h = (float*)(W + o_h);
    float* x2 = (float*)(W + o_x2);
    float* xlo2 = (float*)(W + o_xl2);
    unsigned* scal = (unsigned*)(W + o_sc);
    float* pv1 = (float*)(W + o_p1);
    float* pv2 = (float*)(W + o_p2);
    int* pi1 = (int*)(W + o_i1);
    unsigned long long* packed = (unsigned long long*)(W + o_pk);
    int* wl = (int*)(W + o_wl);
    int* mode = (int*)(W + o_md);
    int* cnt = (int*)(W + o_ct);
    hipMemsetAsync(scal, 0, 16, stream);
    prep_kernel<<<PREP_YB + PREP_XB, 256, 0, stream>>>(y, x, ypk, h, x2, xlo2,
                                                       scal, cnt);
    nnA_mfma<<<(NQ / QB) * NSLICE, BT, 0, stream>>>(x, ypk, h, pv1, pi1, pv2);
    nnB_kernel<<<NQ / 256, 256, 0, stream>>>(x, y, h, lab, pv1, pi1, pv2,
                                             x2, xlo2, scal, out, packed, mode,
                                             wl, cnt);
    nnC_kernel<<<256, 256, 0, stream>>>(x, y, h, wl, cnt, packed);
    nnD_kernel<<<NQ / 256, 256, 0, stream>>>(packed, mode, lab, out);
  } else if (ws_size >= (size_t)NM * 4) {
    float* h = (float*)d_ws;
    hrow_fb<<<NM / 256, 256, 0, stream>>>(y, h);
    nn_fallback<1><<<NQ / 16, 256, 0, stream>>>(x, y, lab, h, out);
  } else {
    nn_fallback<0><<<NQ / 16, 256, 0, stream>>>(x, y, lab, nullptr, out);
  }
}

// Round 11
// 210.294 us; speedup vs baseline: 2.7497x; 1.2996x over previous
//
#include <hip/hip_runtime.h>

// 1-NN via 1-term bf16 MFMA screen (bias-fused, index-stuffed keys) + provable
// per-query Cauchy-Schwarz radius + exact fp32 rescore.
// argmin_j ||x-y_j||^2 == argmin_j (0.5||y_j||^2 - x.y_j).
// Pass A: MFMA computes key_j = 512 + h_j - xhi.yhi directly (C init = h+512,
//   A = -xhi); low 10 mantissa bits carry slice-local j (one v_bfi), so a plain
//   fminf/fmed3 tracks (top-2 value, argmin idx) with exact earliest-j ties.
// Pass B: EPS_q = 2*CSbound*1.01 + 0.02 + 0.30(quant); classify only:
//   lone candidate -> write label; singles -> (q,j) pair worklist (nnS, wave-
//   parallel exact dot); slices w/ >=2 candidates -> slice worklist (nnC).
// Round 11: round 10 was VALU-bound on min-track (5 ops/val vs 4.85cyc MFMA)
// and tail-bound on nnB's serial dots. Key-stuffing cuts mintrack to ~3 ops,
// NSLICE=32 lifts occupancy (5 blocks/CU), nnS parallelizes the tail.

#define NQ 8192
#define NM 32768
#define ND 128
#define BT 128                // nnA block: 2 waves
#define NSLICE 32
#define SLICE (NM / NSLICE)   // 1024 rows -> 16 chunks of 64
#define QW 64                 // queries per wave
#define QB (QW * 2)           // 128 queries per block
#define CAPS 131072
#define CAPR 32768
#define PREP_YB 512
#define PREP_XB 128

using bf16x8 = __attribute__((ext_vector_type(8))) short;
using f32x4  = __attribute__((ext_vector_type(4))) float;

__device__ __forceinline__ unsigned short bf16r(float f) {
  unsigned u = __float_as_uint(f);
  u += 0x7FFFu + ((u >> 16) & 1u);
  return (unsigned short)(u >> 16);
}
__device__ __forceinline__ float bf2f(unsigned short h) {
  return __uint_as_float(((unsigned)h) << 16);
}
__device__ __forceinline__ unsigned long long packsd(float s, int j) {
  unsigned u = __float_as_uint(s);
  u ^= (u & 0x80000000u) ? 0xFFFFFFFFu : 0x80000000u;  // monotone float->uint
  return (((unsigned long long)u) << 32) | (unsigned)j;
}
__device__ __forceinline__ void gload_lds16(const void* g, void* l) {
  __builtin_amdgcn_global_load_lds(
      (const __attribute__((address_space(1))) void*)g,
      (__attribute__((address_space(3))) void*)l, 16, 0, 0);
}

// ---- prep: y -> packed bf16 hi ypk[rg][ks][lane][8], h[j]=0.5||y||^2,
//      global maxes of ||y||^2/||ylo||^2; x -> per-query ||x||^2, ||xlo||^2.
__global__ __launch_bounds__(256) void prep_kernel(
    const float* __restrict__ y, const float* __restrict__ x,
    unsigned short* __restrict__ ypk, float* __restrict__ h,
    float* __restrict__ x2, float* __restrict__ xlo2,
    unsigned* __restrict__ scal, int* __restrict__ cnts) {
  const int wv = threadIdx.x >> 6, l = threadIdx.x & 63;
  if (blockIdx.x == 0 && threadIdx.x == 0) { cnts[0] = 0; cnts[1] = 0; }
  if (blockIdx.x < PREP_YB) {
    __shared__ float bm[4][2];
    float ms = 0.f, mslo = 0.f;
    const int j00 = blockIdx.x * 64 + wv * 16;
#pragma unroll
    for (int r = 0; r < 16; ++r) {
      const int j = j00 + r;
      const float2 v = *(const float2*)(y + (size_t)j * ND + l * 2);
      const unsigned short hb0 = bf16r(v.x), hb1 = bf16r(v.y);
      const float lo0 = v.x - bf2f(hb0), lo1 = v.y - bf2f(hb1);
      const int c0 = l * 2;
      const int idx = ((j >> 4) * 2048) + ((c0 >> 5) * 512) +
                      ((((c0 >> 3) & 3) * 16 + (j & 15)) * 8) + (c0 & 7);
      *(unsigned*)&ypk[idx] = (unsigned)hb0 | ((unsigned)hb1 << 16);
      float s = fmaf(v.y, v.y, v.x * v.x);
      float slo = fmaf(lo1, lo1, lo0 * lo0);
      for (int off = 32; off; off >>= 1) {
        s += __shfl_xor(s, off);
        slo += __shfl_xor(slo, off);
      }
      if (l == 0) h[j] = 0.5f * s;
      ms = fmaxf(ms, s);
      mslo = fmaxf(mslo, slo);
    }
    if (l == 0) { bm[wv][0] = ms; bm[wv][1] = mslo; }
    __syncthreads();
    if (threadIdx.x == 0) {
      float a = bm[0][0], b = bm[0][1];
#pragma unroll
      for (int w2 = 1; w2 < 4; ++w2) { a = fmaxf(a, bm[w2][0]); b = fmaxf(b, bm[w2][1]); }
      atomicMax(&scal[0], __float_as_uint(a));
      atomicMax(&scal[1], __float_as_uint(b));
    }
  } else {
    const int q00 = (blockIdx.x - PREP_YB) * 64 + wv * 16;
#pragma unroll
    for (int r = 0; r < 16; ++r) {
      const int q = q00 + r;
      const float2 v = *(const float2*)(x + (size_t)q * ND + l * 2);
      const unsigned short hb0 = bf16r(v.x), hb1 = bf16r(v.y);
      const float lo0 = v.x - bf2f(hb0), lo1 = v.y - bf2f(hb1);
      float s = fmaf(v.y, v.y, v.x * v.x);
      float slo = fmaf(lo1, lo1, lo0 * lo0);
      for (int off = 32; off; off >>= 1) {
        s += __shfl_xor(s, off);
        slo += __shfl_xor(slo, off);
      }
      if (l == 0) { x2[q] = s; xlo2[q] = slo; }
    }
  }
}

// ---- pass A ----
// LDS chunk (shorts): [rg(4)][ks(4)][lane(64)][8] = 8192 shorts = 16KB.
#define LDFR(FH, ST) do {                                                      \
    _Pragma("unroll")                                                          \
    for (int ks = 0; ks < 4; ++ks)                                            \
      FH[ks] = *(const bf16x8*)&bufc[(ST) * 2048 + ks * 512 + lane * 8];       \
  } while (0)

#define MFST(FH, ST) do {                                                      \
    const float K_ = hv[ST];                                                   \
    f32x4 a0 = {K_, K_, K_, K_}, a1 = {K_, K_, K_, K_};                        \
    f32x4 a2 = {K_, K_, K_, K_}, a3 = {K_, K_, K_, K_};                        \
    __builtin_amdgcn_s_setprio(1);                                             \
    _Pragma("unroll")                                                          \
    for (int ks = 0; ks < 4; ++ks) {                                           \
      a0 = __builtin_amdgcn_mfma_f32_16x16x32_bf16(xn_[0][ks], FH[ks], a0, 0, 0, 0); \
      a1 = __builtin_amdgcn_mfma_f32_16x16x32_bf16(xn_[1][ks], FH[ks], a1, 0, 0, 0); \
      a2 = __builtin_amdgcn_mfma_f32_16x16x32_bf16(xn_[2][ks], FH[ks], a2, 0, 0, 0); \
      a3 = __builtin_amdgcn_mfma_f32_16x16x32_bf16(xn_[3][ks], FH[ks], a3, 0, 0, 0); \
    }                                                                          \
    __builtin_amdgcn_s_setprio(0);                                             \
    const unsigned jc_ = (unsigned)((it * 64 + (ST) * 16 + l15) & (SLICE - 1));\
    _Pragma("unroll")                                                          \
    for (int p = 0; p < 16; ++p) {                                             \
      const float aa = (p < 4) ? a0[p & 3] : (p < 8) ? a1[p & 3]               \
                       : (p < 12) ? a2[p & 3] : a3[p & 3];                     \
      const float key = __uint_as_float(                                       \
          (__float_as_uint(aa) & 0xFFFFFC00u) | jc_);  /* v_bfi */             \
      v2[p] = __builtin_amdgcn_fmed3f(v1[p], v2[p], key);                      \
      v1[p] = fminf(v1[p], key);                                               \
    }                                                                          \
  } while (0)

__global__ __launch_bounds__(BT, 2) void nnA_mfma(
    const float* __restrict__ x, const unsigned short* __restrict__ ypk,
    const float* __restrict__ h,
    float* __restrict__ pv1, float* __restrict__ pv2) {
  __shared__ unsigned short yl2[2][8192];
  const int t = threadIdx.x, lane = t & 63, w = t >> 6;
  const int l15 = lane & 15, lg = lane >> 4;
  const int slice = blockIdx.x & (NSLICE - 1);
  const int q0 = (blockIdx.x >> 5) * QB + w * QW;

  // NEGATED x hi fragments (A-frag row=query l15, k=ks*32+lg*8+i)
  bf16x8 xn_[4][4];
#pragma unroll
  for (int qt = 0; qt < 4; ++qt)
#pragma unroll
    for (int ks = 0; ks < 4; ++ks) {
      const float* xp = x + (size_t)(q0 + qt * 16 + l15) * ND + ks * 32 + lg * 8;
      const float4 f0 = *(const float4*)xp;
      const float4 f1 = *(const float4*)(xp + 4);
      const float ff[8] = {f0.x, f0.y, f0.z, f0.w, f1.x, f1.y, f1.z, f1.w};
      bf16x8 vh;
#pragma unroll
      for (int i = 0; i < 8; ++i)
        vh[i] = (short)(bf16r(ff[i]) ^ 0x8000u);  // bf16 negate = sign flip
      xn_[qt][ks] = vh;
    }

  float v1[16], v2[16];
#pragma unroll
  for (int p = 0; p < 16; ++p) { v1[p] = 3.4e38f; v2[p] = 3.4e38f; }

  const size_t sbase = (size_t)slice * (SLICE / 16) * 2048;
  {
    const unsigned short* src = ypk + sbase + w * 4096 + lane * 8;
#pragma unroll
    for (int s = 0; s < 8; ++s)
      gload_lds16(src + s * 512, &yl2[0][w * 4096 + s * 512]);
  }
  __syncthreads();

#pragma unroll 1
  for (int it = 0; it < SLICE / 64; ++it) {
    const int cur = it & 1;
    if (it < SLICE / 64 - 1) {
      const unsigned short* src =
          ypk + sbase + (size_t)(it + 1) * 8192 + w * 4096 + lane * 8;
      unsigned short* dst = &yl2[cur ^ 1][w * 4096];
#pragma unroll
      for (int s = 0; s < 8; ++s)
        gload_lds16(src + s * 512, dst + s * 512);
    }
    const int jb = slice * SLICE + it * 64;
    float hv[4];
#pragma unroll
    for (int st = 0; st < 4; ++st) hv[st] = h[jb + st * 16 + l15] + 512.0f;

    const unsigned short* __restrict__ bufc = &yl2[cur][0];
    bf16x8 FA[4], FB[4];
    LDFR(FA, 0);
    LDFR(FB, 1);
    MFST(FA, 0);
    LDFR(FA, 2);
    MFST(FB, 1);
    LDFR(FB, 3);
    MFST(FA, 2);
    MFST(FB, 3);
    __syncthreads();
  }

  // Reduce across the 16 lanes sharing each query (keys are positive floats
  // with stuffed idx: fminf gives exact (value, earliest-j) lex min).
#pragma unroll
  for (int p = 0; p < 16; ++p) {
    float m1 = v1[p], m2 = v2[p];
    for (int off = 1; off < 16; off <<= 1) {
      const float o1 = __shfl_xor(m1, off);
      const float o2 = __shfl_xor(m2, off);
      m2 = fminf(fmaxf(m1, o1), fminf(m2, o2));
      m1 = fminf(m1, o1);
    }
    if (l15 == 0) {
      const int q = q0 + (p >> 2) * 16 + lg * 4 + (p & 3);
      pv1[(size_t)q * NSLICE + slice] = m1;
      pv2[(size_t)q * NSLICE + slice] = m2;
    }
  }
}

// exact fp32 key; k-ascending serial chain (used by nnB fallback and nnC)
__device__ __forceinline__ unsigned long long exact_key(
    const float* __restrict__ x, const float* __restrict__ y,
    const float* __restrict__ h, int q, int j) {
  const float* xp = x + (size_t)q * ND;
  const float* yp = y + (size_t)j * ND;
  float dot = 0.f;
#pragma unroll
  for (int k = 0; k < ND; ++k) dot = fmaf(xp[k], yp[k], dot);
  return packsd(h[j] - dot, j);
}

// ---- pass B: classify only; push pair/slice worklists ----
__global__ void nnB_kernel(const float* __restrict__ x, const float* __restrict__ y,
                           const float* __restrict__ h, const float* __restrict__ lab,
                           const float* __restrict__ pv1, const float* __restrict__ pv2,
                           const float* __restrict__ x2, const float* __restrict__ xlo2,
                           const unsigned* __restrict__ scal,
                           float* __restrict__ out,
                           unsigned long long* __restrict__ packed,
                           int* __restrict__ mode, int* __restrict__ wlS,
                           int* __restrict__ wlR, int* __restrict__ cnts) {
  const int q = blockIdx.x * blockDim.x + threadIdx.x;
  if (q >= NQ) return;
  const float maxY = sqrtf(__uint_as_float(scal[0]));
  const float maxYlo = sqrtf(__uint_as_float(scal[1]));
  const float ex = sqrtf(x2[q]), exl = sqrtf(xlo2[q]);
  // hard bound: |key - (512+D)| <= (||x||+||xlo||)maxYlo + ||xlo||maxY (+quant)
  const float epsq = 2.0f * ((ex + exl) * maxYlo + exl * maxY) * 1.01f + 0.32f;
  float m = 3.4e38f;
  for (int s = 0; s < NSLICE; ++s) m = fminf(m, pv1[q * NSLICE + s]);
  const float thr = m + epsq;
  int pj[NSLICE], rs[NSLICE], np = 0, nr = 0;
  for (int s = 0; s < NSLICE; ++s) {
    const float p1 = pv1[q * NSLICE + s];
    if (p1 <= thr) {
      if (pv2[q * NSLICE + s] <= thr) rs[nr++] = s;
      else pj[np++] = s * SLICE + (int)(__float_as_uint(p1) & (SLICE - 1));
    }
  }
  if (nr == 0 && np == 1) { out[q] = lab[pj[0]]; mode[q] = 0; return; }
  mode[q] = 1;
  packed[q] = ~0ull;
  const int baseS = atomicAdd(&cnts[0], np);
  for (int i = 0; i < np; ++i)
    if (baseS + i < CAPS) wlS[baseS + i] = (q << 15) | pj[i];
  const int baseR = atomicAdd(&cnts[1], nr);
  for (int i = 0; i < nr; ++i)
    if (baseR + i < CAPR) wlR[baseR + i] = (q << 5) | rs[i];
  if (baseS + np > CAPS || baseR + nr > CAPR) {
    // overflow safety (practically never): resolve fully serial, exact
    unsigned long long b = ~0ull;
    for (int i = 0; i < np; ++i) {
      const unsigned long long k = exact_key(x, y, h, q, pj[i]);
      b = k < b ? k : b;
    }
    for (int i = 0; i < nr; ++i)
      for (int j = rs[i] * SLICE; j < rs[i] * SLICE + SLICE; ++j) {
        const unsigned long long k = exact_key(x, y, h, q, j);
        b = k < b ? k : b;
      }
    out[q] = lab[(unsigned)(b & 0xFFFFFFFFull)];
    mode[q] = 0;
  }
}

// ---- pass S: wave-per-(q,j) exact dot (coalesced), atomicMin ----
__global__ __launch_bounds__(256) void nnS_kernel(
    const float* __restrict__ x, const float* __restrict__ y,
    const float* __restrict__ h, const int* __restrict__ wlS,
    const int* __restrict__ cnts, unsigned long long* __restrict__ packed) {
  int n = cnts[0];
  if (n > CAPS) n = CAPS;
  const int l = threadIdx.x & 63;
  const int wid = (blockIdx.x * blockDim.x + threadIdx.x) >> 6;
  const int nw = (gridDim.x * blockDim.x) >> 6;
  for (int e = wid; e < n; e += nw) {
    const int v = wlS[e];
    const int q = v >> 15, j = v & (NM - 1);
    const float2 xv = *(const float2*)(x + (size_t)q * ND + l * 2);
    const float2 yv = *(const float2*)(y + (size_t)j * ND + l * 2);
    float d = fmaf(xv.y, yv.y, xv.x * yv.x);
    for (int off = 32; off; off >>= 1) d += __shfl_xor(d, off);
    if (l == 0) atomicMin(packed + q, packsd(h[j] - d, j));
  }
}

// ---- pass C: rescan worklist slices (1024 rows), exact fp32, atomicMin ----
__global__ __launch_bounds__(256) void nnC_kernel(
    const float* __restrict__ x, const float* __restrict__ y,
    const float* __restrict__ h, const int* __restrict__ wlR,
    const int* __restrict__ cnts, unsigned long long* __restrict__ packed) {
  __shared__ float xs[ND];
  __shared__ unsigned long long wb[4];
  int n = cnts[1];
  if (n > CAPR) n = CAPR;
  const int t = threadIdx.x, lane = t & 63, w = t >> 6;
  for (int e = blockIdx.x; e < n; e += gridDim.x) {
    const int v = wlR[e], q = v >> 5, sl = v & (NSLICE - 1);
    __syncthreads();
    if (t < ND) xs[t] = x[(size_t)q * ND + t];
    __syncthreads();
    unsigned long long best = ~0ull;
    for (int i = 0; i < SLICE / 256; ++i) {
      const int j = sl * SLICE + i * 256 + t;
      const float* yp = y + (size_t)j * ND;
      float dot = 0.f;
#pragma unroll
      for (int k = 0; k < ND; ++k) dot = fmaf(xs[k], yp[k], dot);
      const unsigned long long kk = packsd(h[j] - dot, j);
      if (kk < best) best = kk;
    }
    for (int off = 32; off; off >>= 1) {
      const unsigned long long o = __shfl_xor(best, off);
      if (o < best) best = o;
    }
    if (lane == 0) wb[w] = best;
    __syncthreads();
    if (t == 0) {
      unsigned long long b = wb[0];
      for (int w2 = 1; w2 < 4; ++w2)
        if (wb[w2] < b) b = wb[w2];
      atomicMin(packed + q, b);
    }
  }
}

// ---- pass D: finalize pending queries ----
__global__ void nnD_kernel(const unsigned long long* __restrict__ packed,
                           const int* __restrict__ mode,
                           const float* __restrict__ lab, float* __restrict__ out) {
  const int q = blockIdx.x * blockDim.x + threadIdx.x;
  if (q >= NQ) return;
  if (mode[q]) out[q] = lab[(unsigned)(packed[q] & 0xFFFFFFFFull)];
}

// ---- fallback (round-2 kernel, known-passing) ----
__global__ void hrow_fb(const float* __restrict__ y, float* __restrict__ h) {
  const int j = blockIdx.x * blockDim.x + threadIdx.x;
  if (j >= NM) return;
  const float4* __restrict__ yp = (const float4*)(y + (size_t)j * ND);
  float s = 0.f;
#pragma unroll
  for (int u = 0; u < ND / 4; ++u) {
    const float4 v = yp[u];
    s = fmaf(v.x, v.x, s); s = fmaf(v.y, v.y, s);
    s = fmaf(v.z, v.z, s); s = fmaf(v.w, v.w, s);
  }
  h[j] = 0.5f * s;
}

template <int USE_H>
__global__ __launch_bounds__(256, 2) void nn_fallback(
    const float* __restrict__ x, const float* __restrict__ y,
    const float* __restrict__ lab, const float* __restrict__ h,
    float* __restrict__ out) {
  const int t = threadIdx.x;
  const int q0 = blockIdx.x * 16;
  float bv[16]; int bi[16];
#pragma unroll
  for (int q = 0; q < 16; ++q) { bv[q] = 3.4e38f; bi[q] = 0; }
  for (int it = 0; it < NM / 512; ++it) {
    const int j0 = it * 512 + t, j1 = j0 + 256;
    const float4* __restrict__ yp0 = (const float4*)(y + (size_t)j0 * ND);
    const float4* __restrict__ yp1 = (const float4*)(y + (size_t)j1 * ND);
    float acc0[16], acc1[16];
#pragma unroll
    for (int q = 0; q < 16; ++q) { acc0[q] = 0.f; acc1[q] = 0.f; }
    float y20 = 0.f, y21 = 0.f;
#pragma unroll 1
    for (int kc = 0; kc < 4; ++kc) {
      float4 a0[8], a1[8];
#pragma unroll
      for (int u = 0; u < 8; ++u) { a0[u] = yp0[kc * 8 + u]; a1[u] = yp1[kc * 8 + u]; }
      if (USE_H == 0) {
#pragma unroll
        for (int u = 0; u < 8; ++u) {
          y20 = fmaf(a0[u].x, a0[u].x, y20); y20 = fmaf(a0[u].y, a0[u].y, y20);
          y20 = fmaf(a0[u].z, a0[u].z, y20); y20 = fmaf(a0[u].w, a0[u].w, y20);
          y21 = fmaf(a1[u].x, a1[u].x, y21); y21 = fmaf(a1[u].y, a1[u].y, y21);
          y21 = fmaf(a1[u].z, a1[u].z, y21); y21 = fmaf(a1[u].w, a1[u].w, y21);
        }
      }
#pragma unroll
      for (int q = 0; q < 16; ++q) {
        const float* __restrict__ xq = x + (size_t)(q0 + q) * ND + kc * 32;
        float s0 = acc0[q], s1 = acc1[q];
#pragma unroll
        for (int u = 0; u < 8; ++u) {
          const float4 xv = *(const float4*)(xq + u * 4);
          s0 = fmaf(a0[u].x, xv.x, s0); s0 = fmaf(a0[u].y, xv.y, s0);
          s0 = fmaf(a0[u].z, xv.z, s0); s0 = fmaf(a0[u].w, xv.w, s0);
          s1 = fmaf(a1[u].x, xv.x, s1); s1 = fmaf(a1[u].y, xv.y, s1);
          s1 = fmaf(a1[u].z, xv.z, s1); s1 = fmaf(a1[u].w, xv.w, s1);
        }
        acc0[q] = s0; acc1[q] = s1;
      }
    }
    float h0, h1;
    if (USE_H) { h0 = h[j0]; h1 = h[j1]; }
    else { h0 = 0.5f * y20; h1 = 0.5f * y21; }
#pragma unroll
    for (int q = 0; q < 16; ++q) {
      const float s0 = h0 - acc0[q], s1 = h1 - acc1[q];
      if (s0 < bv[q]) { bv[q] = s0; bi[q] = j0; }
      if (s1 < bv[q]) { bv[q] = s1; bi[q] = j1; }
    }
  }
  __shared__ float rv[4][16];
  __shared__ int ri[4][16];
  const int lane = t & 63, w = t >> 6;
#pragma unroll
  for (int q = 0; q < 16; ++q) {
    float v = bv[q]; int ixq = bi[q];
    for (int off = 32; off; off >>= 1) {
      const float ov = __shfl_down(v, off);
      const int oi = __shfl_down(ixq, off);
      if (ov < v || (ov == v && oi < ixq)) { v = ov; ixq = oi; }
    }
    if (lane == 0) { rv[w][q] = v; ri[w][q] = ixq; }
  }
  __syncthreads();
  if (t < 16) {
    float v = rv[0][t]; int ixq = ri[0][t];
#pragma unroll
    for (int w2 = 1; w2 < 4; ++w2) {
      const float ov = rv[w2][t]; const int oi = ri[w2][t];
      if (ov < v || (ov == v && oi < ixq)) { v = ov; ixq = oi; }
    }
    out[q0 + t] = lab[ixq];
  }
}

extern "C" void kernel_launch(void* const* d_in, const int* in_sizes, int n_in,
                              void* d_out, int out_size, void* d_ws, size_t ws_size,
                              hipStream_t stream) {
  const float* x = (const float*)d_in[0];
  const float* y = (const float*)d_in[1];
  const float* lab = (const float*)d_in[2];
  float* out = (float*)d_out;

  const size_t o_ypk = 0;                                // 8 MB hi-only packed
  const size_t o_h   = o_ypk + (size_t)NM * ND * 2;
  const size_t o_x2  = o_h + (size_t)NM * 4;
  const size_t o_xl2 = o_x2 + (size_t)NQ * 4;
  const size_t o_sc  = o_xl2 + (size_t)NQ * 4;
  const size_t o_p1  = o_sc + 16;
  const size_t o_p2  = o_p1 + (size_t)NQ * NSLICE * 4;   // 1 MB
  const size_t o_pk  = o_p2 + (size_t)NQ * NSLICE * 4;   // 1 MB
  const size_t o_wlS = o_pk + (size_t)NQ * 8;
  const size_t o_wlR = o_wlS + (size_t)CAPS * 4;
  const size_t o_md  = o_wlR + (size_t)CAPR * 4;
  const size_t o_ct  = o_md + (size_t)NQ * 4;
  const size_t need  = o_ct + 16;

  if (ws_size >= need) {
    char* W = (char*)d_ws;
    unsigned short* ypk = (unsigned short*)(W + o_ypk);
    float* h = (float*)(W + o_h);
    float* x2 = (float*)(W + o_x2);
    float* xlo2 = (float*)(W + o_xl2);
    unsigned* scal = (unsigned*)(W + o_sc);
    float* pv1 = (float*)(W + o_p1);
    float* pv2 = (float*)(W + o_p2);
    unsigned long long* packed = (unsigned long long*)(W + o_pk);
    int* wlS = (int*)(W + o_wlS);
    int* wlR = (int*)(W + o_wlR);
    int* mode = (int*)(W + o_md);
    int* cnts = (int*)(W + o_ct);
    hipMemsetAsync(scal, 0, 16, stream);
    prep_kernel<<<PREP_YB + PREP_XB, 256, 0, stream>>>(y, x, ypk, h, x2, xlo2,
                                                       scal, cnts);
    nnA_mfma<<<(NQ / QB) * NSLICE, BT, 0, stream>>>(x, ypk, h, pv1, pv2);
    nnB_kernel<<<NQ / 256, 256, 0, stream>>>(x, y, h, lab, pv1, pv2,
                                             x2, xlo2, scal, out, packed, mode,
                                             wlS, wlR, cnts);
    nnS_kernel<<<256, 256, 0, stream>>>(x, y, h, wlS, cnts, packed);
    nnC_kernel<<<256, 256, 0, stream>>>(x, y, h, wlR, cnts, packed);
    nnD_kernel<<<NQ / 256, 256, 0, stream>>>(packed, mode, lab, out);
  } else if (ws_size >= (size_t)NM * 4) {
    float* h = (float*)d_ws;
    hrow_fb<<<NM / 256, 256, 0, stream>>>(y, h);
    nn_fallback<1><<<NQ / 16, 256, 0, stream>>>(x, y, lab, h, out);
  } else {
    nn_fallback<0><<<NQ / 16, 256, 0, stream>>>(x, y, lab, nullptr, out);
  }
}